// Round 1
// baseline (767.948 us; speedup 1.0000x reference)
//
#include <hip/hip_runtime.h>

typedef unsigned short ushort_t;
typedef __bf16 bf16x8 __attribute__((ext_vector_type(8)));
typedef unsigned short ushort8_t __attribute__((ext_vector_type(8)));
typedef unsigned short ushort4_t __attribute__((ext_vector_type(4)));
typedef float floatx4 __attribute__((ext_vector_type(4)));

__device__ __forceinline__ ushort_t f2bf(float f) {
    unsigned int u = __float_as_uint(f);
    u += 0x7FFFu + ((u >> 16) & 1u);           // round-to-nearest-even
    return (ushort_t)(u >> 16);
}
__device__ __forceinline__ float bf2f(ushort_t b) {
    return __uint_as_float(((unsigned int)b) << 16);
}
__device__ __forceinline__ bf16x8 ld_frag(const ushort_t* p) {
    ushort8_t u = *(const ushort8_t*)p;
    return __builtin_bit_cast(bf16x8, u);
}

// C[M,N] = A[M,K] * B[N,K]^T (+bias). A,B row-major K-contiguous.
// fp32 sources are converted to bf16 while staging into LDS.
template <typename TA, typename TB, bool OUT_BF16, bool HAS_BIAS>
__global__ __launch_bounds__(256) void gemm_bt(const TA* __restrict__ A,
                                               const TB* __restrict__ B,
                                               const float* __restrict__ bias,
                                               void* __restrict__ Cout,
                                               int M, int N, int K) {
    __shared__ __attribute__((aligned(16))) ushort_t As[128 * 32];
    __shared__ __attribute__((aligned(16))) ushort_t Bs[128 * 32];
    const int tid = threadIdx.x;
    const int lane = tid & 63, wave = tid >> 6;
    const int quad = lane >> 4, l16 = lane & 15;
    const int wm = wave & 1, wn = wave >> 1;
    const int m0 = blockIdx.y * 128, n0 = blockIdx.x * 128;

    floatx4 acc[4][4] = {};

    for (int k0 = 0; k0 < K; k0 += 32) {
        __syncthreads();
#pragma unroll
        for (int it = 0; it < 4; ++it) {
            int linear = it * 256 + tid;
            int row = linear >> 3;
            int c = (linear & 7) * 4;
            {
                const TA* src = A + (size_t)(m0 + row) * K + k0 + c;
                ushort4_t v;
                if constexpr (sizeof(TA) == 4) {
                    float4 f = *(const float4*)src;
                    v.x = f2bf(f.x); v.y = f2bf(f.y); v.z = f2bf(f.z); v.w = f2bf(f.w);
                } else {
                    v = *(const ushort4_t*)src;
                }
                *(ushort4_t*)&As[row * 32 + c] = v;
            }
            {
                const TB* src = B + (size_t)(n0 + row) * K + k0 + c;
                ushort4_t v;
                if constexpr (sizeof(TB) == 4) {
                    float4 f = *(const float4*)src;
                    v.x = f2bf(f.x); v.y = f2bf(f.y); v.z = f2bf(f.z); v.w = f2bf(f.w);
                } else {
                    v = *(const ushort4_t*)src;
                }
                *(ushort4_t*)&Bs[row * 32 + c] = v;
            }
        }
        __syncthreads();

        bf16x8 af[4], bfr[4];
#pragma unroll
        for (int mt = 0; mt < 4; ++mt)
            af[mt] = ld_frag(&As[(wm * 64 + mt * 16 + l16) * 32 + quad * 8]);
#pragma unroll
        for (int nt = 0; nt < 4; ++nt)
            bfr[nt] = ld_frag(&Bs[(wn * 64 + nt * 16 + l16) * 32 + quad * 8]);
#pragma unroll
        for (int mt = 0; mt < 4; ++mt)
#pragma unroll
            for (int nt = 0; nt < 4; ++nt)
                acc[mt][nt] = __builtin_amdgcn_mfma_f32_16x16x32_bf16(
                    af[mt], bfr[nt], acc[mt][nt], 0, 0, 0);
    }

#pragma unroll
    for (int mt = 0; mt < 4; ++mt) {
        int row = m0 + wm * 64 + mt * 16 + quad * 4;
#pragma unroll
        for (int nt = 0; nt < 4; ++nt) {
            int col = n0 + wn * 64 + nt * 16 + l16;
            float bv = HAS_BIAS ? bias[col] : 0.0f;
#pragma unroll
            for (int r = 0; r < 4; ++r) {
                float v = acc[mt][nt][r] + bv;
                if constexpr (OUT_BF16)
                    ((ushort_t*)Cout)[(size_t)(row + r) * N + col] = f2bf(v);
                else
                    ((float*)Cout)[(size_t)(row + r) * N + col] = v;
            }
        }
    }
}

// In-place RoPE on q,k halves of qkv (bf16). qkv: (B*T, 3072).
__global__ __launch_bounds__(256) void rope_kernel(ushort_t* __restrict__ qkv) {
    int idx = blockIdx.x * 256 + threadIdx.x;  // 8192*32*32 total
    int i = idx & 31;
    int hh = (idx >> 5) & 31;           // 0..15 q heads, 16..31 k heads
    int row = idx >> 10;                // 0..8191
    int t = row & 2047;
    int col = (hh >> 4) * 1024 + (hh & 15) * 64 + i;
    ushort_t* p1 = qkv + (size_t)row * 3072 + col;
    ushort_t* p2 = p1 + 32;
    float x1 = bf2f(*p1), x2 = bf2f(*p2);
    float af = (i < 16) ? exp2f(-10.0f * (float)i / 15.0f) : 0.0f;
    float theta = (float)t * af;
    float s, c;
    __sincosf(theta, &s, &c);
    // full-precision fallback accuracy is unnecessary at bf16 tolerance,
    // but use libm sin/cos to be safe about range reduction:
    s = sinf(theta); c = cosf(theta);
    float y1 = x1 * c + x2 * s;
    float y2 = -x1 * s + x2 * c;
    *p1 = f2bf(y1);
    *p2 = f2bf(y2);
}

// Flash attention: block = (b, h, q-tile of 64). 4 waves, each a 16-row strip.
__global__ __launch_bounds__(256) void attn_kernel(const ushort_t* __restrict__ qkv,
                                                   ushort_t* __restrict__ y) {
    const int T = 2048, LD = 3072;
    __shared__ __attribute__((aligned(16))) ushort_t Qs[64 * 64];
    __shared__ __attribute__((aligned(16))) ushort_t Ks[64 * 64];
    __shared__ __attribute__((aligned(16))) ushort_t Vts[64 * 64];  // transposed: [d][k]
    __shared__ __attribute__((aligned(16))) ushort_t Ps[4 * 16 * 64];
    const int qt = blockIdx.x, h = blockIdx.y, b = blockIdx.z;
    const int tid = threadIdx.x, lane = tid & 63, wq = tid >> 6;
    const int quad = lane >> 4, l16 = lane & 15;
    const ushort_t* base = qkv + (size_t)b * T * LD;

#pragma unroll
    for (int it = 0; it < 2; ++it) {
        int linear = it * 256 + tid;
        int row = linear >> 3, c0 = (linear & 7) * 8;
        *(ushort8_t*)&Qs[row * 64 + c0] =
            *(const ushort8_t*)&base[(size_t)(qt * 64 + row) * LD + h * 64 + c0];
    }

    floatx4 o[4] = {};
    float m_r[4], l_r[4];
#pragma unroll
    for (int r = 0; r < 4; ++r) { m_r[r] = -3e38f; l_r[r] = 0.0f; }

    for (int kt = 0; kt <= qt; ++kt) {
        __syncthreads();
#pragma unroll
        for (int it = 0; it < 2; ++it) {
            int linear = it * 256 + tid;
            int row = linear >> 3, c0 = (linear & 7) * 8;
            *(ushort8_t*)&Ks[row * 64 + c0] =
                *(const ushort8_t*)&base[(size_t)(kt * 64 + row) * LD + 1024 + h * 64 + c0];
        }
#pragma unroll
        for (int it = 0; it < 4; ++it) {
            int linear = it * 256 + tid;
            int row = linear >> 4, c0 = (linear & 15) * 4;
            ushort4_t v = *(const ushort4_t*)&base[(size_t)(kt * 64 + row) * LD + 2048 + h * 64 + c0];
            Vts[(c0 + 0) * 64 + row] = v.x;
            Vts[(c0 + 1) * 64 + row] = v.y;
            Vts[(c0 + 2) * 64 + row] = v.z;
            Vts[(c0 + 3) * 64 + row] = v.w;
        }
        __syncthreads();

        bf16x8 aq0 = ld_frag(&Qs[(wq * 16 + l16) * 64 + quad * 8]);
        bf16x8 aq1 = ld_frag(&Qs[(wq * 16 + l16) * 64 + 32 + quad * 8]);
        floatx4 s[4];
#pragma unroll
        for (int nt = 0; nt < 4; ++nt) {
            bf16x8 bk0 = ld_frag(&Ks[(nt * 16 + l16) * 64 + quad * 8]);
            bf16x8 bk1 = ld_frag(&Ks[(nt * 16 + l16) * 64 + 32 + quad * 8]);
            floatx4 z = {};
            z = __builtin_amdgcn_mfma_f32_16x16x32_bf16(aq0, bk0, z, 0, 0, 0);
            s[nt] = __builtin_amdgcn_mfma_f32_16x16x32_bf16(aq1, bk1, z, 0, 0, 0);
        }

        const int grow = qt * 64 + wq * 16 + quad * 4;
#pragma unroll
        for (int nt = 0; nt < 4; ++nt) {
            int gcol = kt * 64 + nt * 16 + l16;
#pragma unroll
            for (int r = 0; r < 4; ++r) {
                float v = s[nt][r] * 0.125f;
                if (kt == qt && gcol > grow + r) v = -3e38f;
                s[nt][r] = v;
            }
        }

#pragma unroll
        for (int r = 0; r < 4; ++r) {
            float mx = fmaxf(fmaxf(s[0][r], s[1][r]), fmaxf(s[2][r], s[3][r]));
#pragma unroll
            for (int off = 1; off < 16; off <<= 1)
                mx = fmaxf(mx, __shfl_xor(mx, off));
            float mnew = fmaxf(m_r[r], mx);
            float alpha = __expf(m_r[r] - mnew);
            m_r[r] = mnew;
            float rs = 0.0f;
#pragma unroll
            for (int nt = 0; nt < 4; ++nt) {
                float p = __expf(s[nt][r] - mnew);
                s[nt][r] = p;
                rs += p;
            }
#pragma unroll
            for (int off = 1; off < 16; off <<= 1)
                rs += __shfl_xor(rs, off);
            l_r[r] = l_r[r] * alpha + rs;
#pragma unroll
            for (int nt = 0; nt < 4; ++nt) o[nt][r] *= alpha;
        }

#pragma unroll
        for (int nt = 0; nt < 4; ++nt)
#pragma unroll
            for (int r = 0; r < 4; ++r)
                Ps[wq * 1024 + (quad * 4 + r) * 64 + nt * 16 + l16] = f2bf(s[nt][r]);
        __syncthreads();

#pragma unroll
        for (int kc = 0; kc < 2; ++kc) {
            bf16x8 ap = ld_frag(&Ps[wq * 1024 + l16 * 64 + kc * 32 + quad * 8]);
#pragma unroll
            for (int nt = 0; nt < 4; ++nt) {
                bf16x8 bv = ld_frag(&Vts[(nt * 16 + l16) * 64 + kc * 32 + quad * 8]);
                o[nt] = __builtin_amdgcn_mfma_f32_16x16x32_bf16(ap, bv, o[nt], 0, 0, 0);
            }
        }
    }

#pragma unroll
    for (int nt = 0; nt < 4; ++nt) {
        int col = h * 64 + nt * 16 + l16;
#pragma unroll
        for (int r = 0; r < 4; ++r) {
            int row = b * T + qt * 64 + wq * 16 + quad * 4 + r;
            y[(size_t)row * 1024 + col] = f2bf(o[nt][r] / l_r[r]);
        }
    }
}

extern "C" void kernel_launch(void* const* d_in, const int* in_sizes, int n_in,
                              void* d_out, int out_size, void* d_ws, size_t ws_size,
                              hipStream_t stream) {
    const float* x = (const float*)d_in[0];
    const float* qkv_w = (const float*)d_in[1];
    const float* c_proj_w = (const float*)d_in[2];
    const float* c_proj_b = (const float*)d_in[3];
    float* out = (float*)d_out;

    const int B = 4, T = 2048, C = 1024, H = 16;
    const int M = B * T;  // 8192

    // ws layout: qkv bf16 (M x 3072) = 48 MB, then y bf16 (M x 1024) = 16 MB
    ushort_t* qkv = (ushort_t*)d_ws;
    ushort_t* y = (ushort_t*)((char*)d_ws + (size_t)M * 3072 * 2);

    gemm_bt<float, float, true, false>
        <<<dim3(3072 / 128, M / 128), 256, 0, stream>>>(x, qkv_w, nullptr, qkv, M, 3072, C);

    rope_kernel<<<(M * 32 * 32) / 256, 256, 0, stream>>>(qkv);

    attn_kernel<<<dim3(T / 64, H, B), 256, 0, stream>>>(qkv, y);

    gemm_bt<ushort_t, float, false, true>
        <<<dim3(1024 / 128, M / 128), 256, 0, stream>>>(y, c_proj_w, c_proj_b, out, M, 1024, C);
}

// Round 2
// 623.828 us; speedup vs baseline: 1.2310x; 1.2310x over previous
//
#include <hip/hip_runtime.h>

typedef unsigned short ushort_t;
typedef __bf16 bf16x8 __attribute__((ext_vector_type(8)));
typedef unsigned short ushort8_t __attribute__((ext_vector_type(8)));
typedef unsigned short ushort4_t __attribute__((ext_vector_type(4)));
typedef float floatx4 __attribute__((ext_vector_type(4)));

__device__ __forceinline__ ushort_t f2bf(float f) {
    unsigned int u = __float_as_uint(f);
    u += 0x7FFFu + ((u >> 16) & 1u);           // round-to-nearest-even
    return (ushort_t)(u >> 16);
}
__device__ __forceinline__ float bf2f(ushort_t b) {
    return __uint_as_float(((unsigned int)b) << 16);
}
__device__ __forceinline__ bf16x8 ld_frag(const ushort_t* p) {
    ushort8_t u = *(const ushort8_t*)p;
    return __builtin_bit_cast(bf16x8, u);
}

// ---------------- GEMM (unchanged from round 0) ----------------
// C[M,N] = A[M,K] * B[N,K]^T (+bias). A,B row-major K-contiguous.
template <typename TA, typename TB, bool OUT_BF16, bool HAS_BIAS>
__global__ __launch_bounds__(256) void gemm_bt(const TA* __restrict__ A,
                                               const TB* __restrict__ B,
                                               const float* __restrict__ bias,
                                               void* __restrict__ Cout,
                                               int M, int N, int K) {
    __shared__ __attribute__((aligned(16))) ushort_t As[128 * 32];
    __shared__ __attribute__((aligned(16))) ushort_t Bs[128 * 32];
    const int tid = threadIdx.x;
    const int lane = tid & 63, wave = tid >> 6;
    const int quad = lane >> 4, l16 = lane & 15;
    const int wm = wave & 1, wn = wave >> 1;
    const int m0 = blockIdx.y * 128, n0 = blockIdx.x * 128;

    floatx4 acc[4][4] = {};

    for (int k0 = 0; k0 < K; k0 += 32) {
        __syncthreads();
#pragma unroll
        for (int it = 0; it < 4; ++it) {
            int linear = it * 256 + tid;
            int row = linear >> 3;
            int c = (linear & 7) * 4;
            {
                const TA* src = A + (size_t)(m0 + row) * K + k0 + c;
                ushort4_t v;
                if constexpr (sizeof(TA) == 4) {
                    float4 f = *(const float4*)src;
                    v.x = f2bf(f.x); v.y = f2bf(f.y); v.z = f2bf(f.z); v.w = f2bf(f.w);
                } else {
                    v = *(const ushort4_t*)src;
                }
                *(ushort4_t*)&As[row * 32 + c] = v;
            }
            {
                const TB* src = B + (size_t)(n0 + row) * K + k0 + c;
                ushort4_t v;
                if constexpr (sizeof(TB) == 4) {
                    float4 f = *(const float4*)src;
                    v.x = f2bf(f.x); v.y = f2bf(f.y); v.z = f2bf(f.z); v.w = f2bf(f.w);
                } else {
                    v = *(const ushort4_t*)src;
                }
                *(ushort4_t*)&Bs[row * 32 + c] = v;
            }
        }
        __syncthreads();

        bf16x8 af[4], bfr[4];
#pragma unroll
        for (int mt = 0; mt < 4; ++mt)
            af[mt] = ld_frag(&As[(wm * 64 + mt * 16 + l16) * 32 + quad * 8]);
#pragma unroll
        for (int nt = 0; nt < 4; ++nt)
            bfr[nt] = ld_frag(&Bs[(wn * 64 + nt * 16 + l16) * 32 + quad * 8]);
#pragma unroll
        for (int mt = 0; mt < 4; ++mt)
#pragma unroll
            for (int nt = 0; nt < 4; ++nt)
                acc[mt][nt] = __builtin_amdgcn_mfma_f32_16x16x32_bf16(
                    af[mt], bfr[nt], acc[mt][nt], 0, 0, 0);
    }

#pragma unroll
    for (int mt = 0; mt < 4; ++mt) {
        int row = m0 + wm * 64 + mt * 16 + quad * 4;
#pragma unroll
        for (int nt = 0; nt < 4; ++nt) {
            int col = n0 + wn * 64 + nt * 16 + l16;
            float bv = HAS_BIAS ? bias[col] : 0.0f;
#pragma unroll
            for (int r = 0; r < 4; ++r) {
                float v = acc[mt][nt][r] + bv;
                if constexpr (OUT_BF16)
                    ((ushort_t*)Cout)[(size_t)(row + r) * N + col] = f2bf(v);
                else
                    ((float*)Cout)[(size_t)(row + r) * N + col] = v;
            }
        }
    }
}

// ---------------- RoPE (unchanged) ----------------
__global__ __launch_bounds__(256) void rope_kernel(ushort_t* __restrict__ qkv) {
    int idx = blockIdx.x * 256 + threadIdx.x;
    int i = idx & 31;
    int hh = (idx >> 5) & 31;
    int row = idx >> 10;
    int t = row & 2047;
    int col = (hh >> 4) * 1024 + (hh & 15) * 64 + i;
    ushort_t* p1 = qkv + (size_t)row * 3072 + col;
    ushort_t* p2 = p1 + 32;
    float x1 = bf2f(*p1), x2 = bf2f(*p2);
    float af = (i < 16) ? exp2f(-10.0f * (float)i / 15.0f) : 0.0f;
    float theta = (float)t * af;
    float s = sinf(theta), c = cosf(theta);
    float y1 = x1 * c + x2 * s;
    float y2 = -x1 * s + x2 * c;
    *p1 = f2bf(y1);
    *p2 = f2bf(y2);
}

// ---------------- Flash attention, 128x128 tiles, swizzled LDS ----------------
// Block = (b, h, 128-row q-tile). 4 waves; each wave owns 2 strips of 16 q-rows.
// LDS layout (ushort units), total 32768 ushorts = 64 KB:
//   Ks  [0,     8192)  : 128 x 64, slot(col8) = col8 ^ ((row>>1)&7)   [8-ushort chunks]
//   Vt  [8192, 16384)  : 64(d) x 128(k), slot(k) = k ^ (8*(d>>3))
//   PQ  [16384,32768)  : Qs (128x64, swizzled like Ks) during kt==0; then
//                        Ps: per-wave 32x128, slot(col)=col^(8*((row>>1)&7))
#define SCALE_LOG2E 0.18033688011112042f  /* 0.125 * log2(e) */

__device__ __forceinline__ floatx4 mfma16(bf16x8 a, bf16x8 b, floatx4 c) {
    return __builtin_amdgcn_mfma_f32_16x16x32_bf16(a, b, c, 0, 0, 0);
}

__device__ __forceinline__ void strip_proc(
    floatx4 (&s)[8], floatx4 (&o)[4], float (&mm)[4], float (&ll)[4],
    ushort_t* __restrict__ Pst, const ushort_t* __restrict__ Vt,
    int quad, int l16, int sw8, int lim, int kcmax, bool diag, int rowb) {
    // mask + scale (base-2 domain)
#pragma unroll
    for (int kt8 = 0; kt8 < 8; ++kt8)
        if (kt8 <= lim) {
#pragma unroll
            for (int r = 0; r < 4; ++r) {
                float v = s[kt8][r] * SCALE_LOG2E;
                if (diag && (kt8 * 16 + l16 > rowb + quad * 4 + r)) v = -3e38f;
                s[kt8][r] = v;
            }
        }
    // online softmax (rows live across 16 lanes of a quad)
#pragma unroll
    for (int r = 0; r < 4; ++r) {
        float mx = -3e38f;
#pragma unroll
        for (int kt8 = 0; kt8 < 8; ++kt8)
            if (kt8 <= lim) mx = fmaxf(mx, s[kt8][r]);
#pragma unroll
        for (int off = 8; off; off >>= 1) mx = fmaxf(mx, __shfl_xor(mx, off));
        float mnew = fmaxf(mm[r], mx);
        float alpha = exp2f(mm[r] - mnew);
        mm[r] = mnew;
        float sum = 0.0f;
#pragma unroll
        for (int kt8 = 0; kt8 < 8; ++kt8)
            if (kt8 <= lim) {
                float p = exp2f(s[kt8][r] - mnew);
                s[kt8][r] = p;
                sum += p;
            }
#pragma unroll
        for (int off = 8; off; off >>= 1) sum += __shfl_xor(sum, off);
        ll[r] = ll[r] * alpha + sum;
#pragma unroll
        for (int nt = 0; nt < 4; ++nt) o[nt][r] *= alpha;
    }
    // store P (C-layout scatter, swizzled -> conflict-free 2-way)
#pragma unroll
    for (int kt8 = 0; kt8 < 8; ++kt8)
        if (kt8 <= lim) {
#pragma unroll
            for (int r = 0; r < 4; ++r)
                Pst[(quad * 4 + r) * 128 +
                    ((kt8 * 16 + l16) ^ (16 * quad + 8 * (r >> 1)))] = f2bf(s[kt8][r]);
        }
    if (diag && !(lim & 1)) {  // zero the partially-covered odd tile
        int zt = lim + 1;
#pragma unroll
        for (int r = 0; r < 4; ++r)
            Pst[(quad * 4 + r) * 128 +
                ((zt * 16 + l16) ^ (16 * quad + 8 * (r >> 1)))] = 0;
    }
    // PV: A = P (same-wave LDS RAW, no barrier), B = Vt
#pragma unroll
    for (int kc = 0; kc < 4; ++kc)
        if (kc <= kcmax) {
            bf16x8 ap = ld_frag(&Pst[l16 * 128 + ((kc * 32 + quad * 8) ^ sw8)]);
#pragma unroll
            for (int nt = 0; nt < 4; ++nt) {
                bf16x8 bv = ld_frag(&Vt[(nt * 16 + l16) * 128 +
                                        ((kc * 32 + quad * 8) ^ (8 * (2 * nt + (l16 >> 3))))]);
                o[nt] = mfma16(ap, bv, o[nt]);
            }
        }
}

__global__ __launch_bounds__(256, 2) void attn_kernel(const ushort_t* __restrict__ qkv,
                                                      ushort_t* __restrict__ y) {
    const int T = 2048, LD = 3072;
    __shared__ __attribute__((aligned(16))) ushort_t lds[32768];
    ushort_t* Ks = lds;
    ushort_t* Vt = lds + 8192;
    ushort_t* PQ = lds + 16384;

    const int bq = (int)gridDim.x - 1 - (int)blockIdx.x;  // heavy blocks first
    const int h = blockIdx.y, b = blockIdx.z;
    const int tid = threadIdx.x, lane = tid & 63, wq = tid >> 6;
    const int quad = lane >> 4, l16 = lane & 15;
    const int lrow = lane >> 3, lchunk = lane & 7;
    const int sw8 = 8 * (l16 >> 1);
    const ushort_t* base = qkv + (size_t)b * T * LD;
    ushort_t* Psw = PQ + wq * 4096;  // per-wave 32x128 P buffer (aliases Qs)

    // ---- stage Q once (each wave stages + later reads only its own 32 rows) ----
    {
        const ushort_t* gq = base + (size_t)(bq * 128) * LD + h * 64 + lchunk * 8;
#pragma unroll
        for (int i = 0; i < 4; ++i) {
            int rowloc = wq * 32 + i * 8 + lrow;
            ushort8_t v = *(const ushort8_t*)(gq + (size_t)rowloc * LD);
            *(ushort8_t*)&PQ[rowloc * 64 + 8 * (lchunk ^ ((rowloc >> 1) & 7))] = v;
        }
    }

    floatx4 o[2][4] = {};
    float m_[2][4], l_[2][4];
#pragma unroll
    for (int st = 0; st < 2; ++st)
#pragma unroll
        for (int r = 0; r < 4; ++r) { m_[st][r] = -3e38f; l_[st][r] = 0.0f; }

    bf16x8 aq[2][2];

    for (int kt = 0; kt <= bq; ++kt) {
        __syncthreads();  // previous iteration's K/V reads complete
        // ---- stage K (swizzled, b128 stores) ----
        {
            const ushort_t* gk = base + (size_t)(kt * 128) * LD + 1024 + h * 64 + lchunk * 8;
#pragma unroll
            for (int i = 0; i < 4; ++i) {
                int rowloc = wq * 32 + i * 8 + lrow;
                ushort8_t v = *(const ushort8_t*)(gk + (size_t)rowloc * LD);
                *(ushort8_t*)&Ks[rowloc * 64 + 8 * (lchunk ^ ((rowloc >> 1) & 7))] = v;
            }
        }
        // ---- stage V transposed (scalar stores, swizzle makes them 2-way/free) ----
        {
            const ushort_t* gv = base + (size_t)(kt * 128) * LD + 2048 + h * 64 + lchunk * 8;
#pragma unroll
            for (int i = 0; i < 4; ++i) {
                int rowloc = wq * 32 + i * 8 + lrow;  // k index
                ushort8_t v = *(const ushort8_t*)(gv + (size_t)rowloc * LD);
                int d0 = lchunk * 8;
                int colx = rowloc ^ (8 * lchunk);
#pragma unroll
                for (int j = 0; j < 8; ++j) Vt[(d0 + j) * 128 + colx] = v[j];
            }
        }
        __syncthreads();  // K/V (and Q on first iter) visible

        if (kt == 0) {
#pragma unroll
            for (int st = 0; st < 2; ++st)
#pragma unroll
                for (int kh = 0; kh < 2; ++kh)
                    aq[st][kh] = ld_frag(&PQ[(wq * 32 + st * 16 + l16) * 64 +
                                             ((kh * 32 + quad * 8) ^ sw8)]);
            __syncthreads();  // all Q frag reads done before P stores clobber Qs
        }

        const bool diag = (kt == bq);
        const int limQ = diag ? 2 * wq + 1 : 7;
        const int lim0 = diag ? 2 * wq : 7;

        // ---- QK^T: K-frags shared by both strips ----
        floatx4 s0[8], s1[8];
#pragma unroll
        for (int ktile = 0; ktile < 8; ++ktile) {
            if (ktile <= limQ) {
                const ushort_t* kb = &Ks[(ktile * 16 + l16) * 64];
                bf16x8 bk0 = ld_frag(kb + ((quad * 8) ^ sw8));
                bf16x8 bk1 = ld_frag(kb + ((32 + quad * 8) ^ sw8));
                if (ktile <= lim0) {
                    floatx4 z = {};
                    z = mfma16(aq[0][0], bk0, z);
                    s0[ktile] = mfma16(aq[0][1], bk1, z);
                }
                floatx4 z = {};
                z = mfma16(aq[1][0], bk0, z);
                s1[ktile] = mfma16(aq[1][1], bk1, z);
            }
        }

        const int kcmax = diag ? wq : 3;
        strip_proc(s0, o[0], m_[0], l_[0], Psw, Vt, quad, l16, sw8,
                   lim0, kcmax, diag, wq * 32);
        strip_proc(s1, o[1], m_[1], l_[1], Psw + 2048, Vt, quad, l16, sw8,
                   limQ, kcmax, diag, wq * 32 + 16);
    }

    // ---- epilogue ----
#pragma unroll
    for (int st = 0; st < 2; ++st)
#pragma unroll
        for (int r = 0; r < 4; ++r) {
            float inv = 1.0f / l_[st][r];
            int row = b * T + bq * 128 + wq * 32 + st * 16 + quad * 4 + r;
#pragma unroll
            for (int nt = 0; nt < 4; ++nt) {
                int col = h * 64 + nt * 16 + l16;
                y[(size_t)row * 1024 + col] = f2bf(o[st][nt][r] * inv);
            }
        }
}

extern "C" void kernel_launch(void* const* d_in, const int* in_sizes, int n_in,
                              void* d_out, int out_size, void* d_ws, size_t ws_size,
                              hipStream_t stream) {
    const float* x = (const float*)d_in[0];
    const float* qkv_w = (const float*)d_in[1];
    const float* c_proj_w = (const float*)d_in[2];
    const float* c_proj_b = (const float*)d_in[3];
    float* out = (float*)d_out;

    const int B = 4, T = 2048, C = 1024, H = 16;
    const int M = B * T;  // 8192

    ushort_t* qkv = (ushort_t*)d_ws;                                   // M x 3072 bf16
    ushort_t* y = (ushort_t*)((char*)d_ws + (size_t)M * 3072 * 2);     // M x 1024 bf16

    gemm_bt<float, float, true, false>
        <<<dim3(3072 / 128, M / 128), 256, 0, stream>>>(x, qkv_w, nullptr, qkv, M, 3072, C);

    rope_kernel<<<(M * 32 * 32) / 256, 256, 0, stream>>>(qkv);

    attn_kernel<<<dim3(T / 128, H, B), 256, 0, stream>>>(qkv, y);

    gemm_bt<ushort_t, float, false, true>
        <<<dim3(1024 / 128, M / 128), 256, 0, stream>>>(y, c_proj_w, c_proj_b, out, M, 1024, C);
}

// Round 3
// 543.327 us; speedup vs baseline: 1.4134x; 1.1482x over previous
//
#include <hip/hip_runtime.h>

typedef unsigned short ushort_t;
typedef __bf16 bf16x8 __attribute__((ext_vector_type(8)));
typedef unsigned short ushort8_t __attribute__((ext_vector_type(8)));
typedef unsigned short ushort4_t __attribute__((ext_vector_type(4)));
typedef float floatx4 __attribute__((ext_vector_type(4)));
typedef unsigned int uint4_t __attribute__((ext_vector_type(4)));
typedef unsigned int uint2_t __attribute__((ext_vector_type(2)));

__device__ __forceinline__ ushort_t f2bf(float f) {
    unsigned int u = __float_as_uint(f);
    u += 0x7FFFu + ((u >> 16) & 1u);  // RNE
    return (ushort_t)(u >> 16);
}
__device__ __forceinline__ float bf2f(ushort_t b) {
    return __uint_as_float(((unsigned int)b) << 16);
}
__device__ __forceinline__ bf16x8 ld_frag(const ushort_t* p) {
    ushort8_t u = *(const ushort8_t*)p;
    return __builtin_bit_cast(bf16x8, u);
}
// pack two f32 -> two bf16 (truncation) in one v_perm
__device__ __forceinline__ unsigned pack_trunc(float lo, float hi) {
    return __builtin_amdgcn_perm(__float_as_uint(hi), __float_as_uint(lo), 0x07060302u);
}
__device__ __forceinline__ floatx4 mfma16(bf16x8 a, bf16x8 b, floatx4 c) {
    return __builtin_amdgcn_mfma_f32_16x16x32_bf16(a, b, c, 0, 0, 0);
}

// ---------------- GEMM: C[M,N] = A[M,K]*B[N,K]^T ----------------
// MODE 0: f32 out (ld N) + bias.  MODE 2: qkv-split: cols<2048 -> qk bf16 (ld 2048),
// cols>=2048 -> vt transposed bf16 [b][h][d][t].
template <typename TA, int MODE>
__global__ __launch_bounds__(256) void gemm_bt(const TA* __restrict__ A,
                                               const float* __restrict__ B,
                                               const float* __restrict__ bias,
                                               void* __restrict__ Cout,
                                               ushort_t* __restrict__ vt,
                                               int M, int N, int K) {
    __shared__ __attribute__((aligned(16))) ushort_t As[128 * 32];
    __shared__ __attribute__((aligned(16))) ushort_t Bs[128 * 32];
    const int tid = threadIdx.x;
    const int lane = tid & 63, wave = tid >> 6;
    const int quad = lane >> 4, l16 = lane & 15;
    const int wm = wave & 1, wn = wave >> 1;
    const int m0 = blockIdx.y * 128, n0 = blockIdx.x * 128;

    floatx4 acc[4][4] = {};

    for (int k0 = 0; k0 < K; k0 += 32) {
        __syncthreads();
#pragma unroll
        for (int it = 0; it < 4; ++it) {
            int linear = it * 256 + tid;
            int row = linear >> 3;
            int c = (linear & 7) * 4;
            {
                const TA* src = A + (size_t)(m0 + row) * K + k0 + c;
                ushort4_t v;
                if constexpr (sizeof(TA) == 4) {
                    float4 f = *(const float4*)src;
                    v.x = f2bf(f.x); v.y = f2bf(f.y); v.z = f2bf(f.z); v.w = f2bf(f.w);
                } else {
                    v = *(const ushort4_t*)src;
                }
                *(ushort4_t*)&As[row * 32 + c] = v;
            }
            {
                const float* src = B + (size_t)(n0 + row) * K + k0 + c;
                float4 f = *(const float4*)src;
                ushort4_t v;
                v.x = f2bf(f.x); v.y = f2bf(f.y); v.z = f2bf(f.z); v.w = f2bf(f.w);
                *(ushort4_t*)&Bs[row * 32 + c] = v;
            }
        }
        __syncthreads();

        bf16x8 af[4], bfr[4];
#pragma unroll
        for (int mt = 0; mt < 4; ++mt)
            af[mt] = ld_frag(&As[(wm * 64 + mt * 16 + l16) * 32 + quad * 8]);
#pragma unroll
        for (int nt = 0; nt < 4; ++nt)
            bfr[nt] = ld_frag(&Bs[(wn * 64 + nt * 16 + l16) * 32 + quad * 8]);
#pragma unroll
        for (int mt = 0; mt < 4; ++mt)
#pragma unroll
            for (int nt = 0; nt < 4; ++nt)
                acc[mt][nt] = mfma16(af[mt], bfr[nt], acc[mt][nt]);
    }

#pragma unroll
    for (int mt = 0; mt < 4; ++mt) {
        int row = m0 + wm * 64 + mt * 16 + quad * 4;
#pragma unroll
        for (int nt = 0; nt < 4; ++nt) {
            int nglob = n0 + wn * 64 + nt * 16 + l16;
            if constexpr (MODE == 0) {
                float bv = bias ? bias[nglob] : 0.0f;
#pragma unroll
                for (int r = 0; r < 4; ++r)
                    ((float*)Cout)[(size_t)(row + r) * N + nglob] = acc[mt][nt][r] + bv;
            } else {
                if (nglob < 2048) {
#pragma unroll
                    for (int r = 0; r < 4; ++r)
                        ((ushort_t*)Cout)[(size_t)(row + r) * 2048 + nglob] =
                            f2bf(acc[mt][nt][r]);
                } else {
                    int d = nglob & 63, hh = (nglob >> 6) & 15;
                    int bb = row >> 11, t = row & 2047;
                    ushort4_t pk;
                    pk.x = f2bf(acc[mt][nt][0]);
                    pk.y = f2bf(acc[mt][nt][1]);
                    pk.z = f2bf(acc[mt][nt][2]);
                    pk.w = f2bf(acc[mt][nt][3]);
                    *(ushort4_t*)&vt[(((size_t)bb * 16 + hh) * 64 + d) * 2048 + t] = pk;
                }
            }
        }
    }
}

// ---------------- RoPE (in-place on qk buffer, ld 2048) ----------------
__global__ __launch_bounds__(256) void rope_kernel(ushort_t* __restrict__ qk) {
    int idx = blockIdx.x * 256 + threadIdx.x;
    int i = idx & 31;
    int hh = (idx >> 5) & 31;  // 0..15 q heads, 16..31 k heads
    int row = idx >> 10;
    int t = row & 2047;
    int col = hh * 64 + i;
    ushort_t* p1 = qk + (size_t)row * 2048 + col;
    ushort_t* p2 = p1 + 32;
    float x1 = bf2f(*p1), x2 = bf2f(*p2);
    float af = (i < 16) ? exp2f(-10.0f * (float)i / 15.0f) : 0.0f;
    float theta = (float)t * af;
    float s = sinf(theta), c = cosf(theta);
    *p1 = f2bf(x1 * c + x2 * s);
    *p2 = f2bf(-x1 * s + x2 * c);
}

// ---------------- Flash attention: independent waves, no barriers ----------------
// Wave-unit = 32 q-rows of one (b,h). S^T = K*Q^T via MFMA (K = A-operand, direct
// global loads); softmax reduction depth 2 (cross-quad shuffles); l via ones-column
// MFMA; P through per-wave LDS (stride 136, b128-aligned); V^T direct global.
#define ATT_SCALE 0.18033688011112042f  /* 0.125 * log2(e) */

template <bool DIAG>
__device__ __forceinline__ void attn_step(
    const ushort_t* __restrict__ kb, const ushort_t* __restrict__ vb,
    ushort_t* __restrict__ Pw, const bf16x8 (&qf)[2][2],
    floatx4 (&o)[2][4], floatx4 (&lac)[2], float (&m_)[2],
    int quad, int l16, int mhi, int qrel) {
    ushort8_t ou;
#pragma unroll
    for (int j = 0; j < 8; ++j) ou[j] = 0x3F80;  // bf16 1.0
    const bf16x8 vONE = __builtin_bit_cast(bf16x8, ou);

    floatx4 s[8][2];
#pragma unroll
    for (int mt = 0; mt < 8; ++mt) {
        if (DIAG && mt > mhi) continue;
        const ushort_t* kr = kb + (size_t)(mt * 16 + l16) * 2048;
        bf16x8 k0 = ld_frag(kr);
        bf16x8 k1 = ld_frag(kr + 32);
#pragma unroll
        for (int nt = 0; nt < 2; ++nt) {
            floatx4 z = {};
            z = mfma16(k0, qf[nt][0], z);
            s[mt][nt] = mfma16(k1, qf[nt][1], z);
        }
    }
    if (DIAG) {
#pragma unroll
        for (int mt = 0; mt < 8; ++mt) {
            if (mt > mhi) continue;
#pragma unroll
            for (int nt = 0; nt < 2; ++nt)
#pragma unroll
                for (int r = 0; r < 4; ++r)
                    if (mt * 16 + quad * 4 + r > qrel + nt * 16 + l16)
                        s[mt][nt][r] = -3e38f;
        }
    }
    float alpha_l[2];
#pragma unroll
    for (int nt = 0; nt < 2; ++nt) {
        float mx = -3e38f;
#pragma unroll
        for (int mt = 0; mt < 8; ++mt) {
            if (DIAG && mt > mhi) continue;
            mx = fmaxf(mx, fmaxf(fmaxf(s[mt][nt][0], s[mt][nt][1]),
                                 fmaxf(s[mt][nt][2], s[mt][nt][3])));
        }
        mx = fmaxf(mx, __shfl_xor(mx, 16));
        mx = fmaxf(mx, __shfl_xor(mx, 32));
        float mnew = fmaxf(m_[nt], mx);
        alpha_l[nt] = __builtin_amdgcn_exp2f(m_[nt] - mnew);
        m_[nt] = mnew;
#pragma unroll
        for (int mt = 0; mt < 8; ++mt) {
            if (DIAG && mt > mhi) continue;
#pragma unroll
            for (int r = 0; r < 4; ++r)
                s[mt][nt][r] = __builtin_amdgcn_exp2f(s[mt][nt][r] - mnew);
        }
    }
    // rescale o/lac: move alpha from l16-domain to C-row domain
#pragma unroll
    for (int mtq = 0; mtq < 2; ++mtq)
#pragma unroll
        for (int r = 0; r < 4; ++r) {
            float ao = __shfl(alpha_l[mtq], quad * 4 + r);
            lac[mtq][r] *= ao;
#pragma unroll
            for (int ntd = 0; ntd < 4; ++ntd) o[mtq][ntd][r] *= ao;
        }
    // pack P (truncation) -> per-wave LDS
#pragma unroll
    for (int mt = 0; mt < 8; ++mt) {
        if (DIAG && mt > mhi) continue;
#pragma unroll
        for (int nt = 0; nt < 2; ++nt) {
            uint2_t pk;
            pk.x = pack_trunc(s[mt][nt][0], s[mt][nt][1]);
            pk.y = pack_trunc(s[mt][nt][2], s[mt][nt][3]);
            *(uint2_t*)&Pw[(nt * 16 + l16) * 136 + mt * 16 + quad * 4] = pk;
        }
    }
    // PV + l (ones-column); same-wave LDS RAW needs no barrier
#pragma unroll
    for (int kc = 0; kc < 4; ++kc) {
        if (DIAG && kc > (mhi >> 1)) continue;
        bf16x8 ap0 = ld_frag(&Pw[l16 * 136 + kc * 32 + quad * 8]);
        bf16x8 ap1 = ld_frag(&Pw[(16 + l16) * 136 + kc * 32 + quad * 8]);
        lac[0] = mfma16(ap0, vONE, lac[0]);
        lac[1] = mfma16(ap1, vONE, lac[1]);
#pragma unroll
        for (int ntd = 0; ntd < 4; ++ntd) {
            bf16x8 bv = ld_frag(vb + (size_t)(ntd * 16 + l16) * 2048 + kc * 32);
            o[0][ntd] = mfma16(ap0, bv, o[0][ntd]);
            o[1][ntd] = mfma16(ap1, bv, o[1][ntd]);
        }
    }
}

__global__ __launch_bounds__(256, 3) void attn_kernel(const ushort_t* __restrict__ qk,
                                                      const ushort_t* __restrict__ vt,
                                                      ushort_t* __restrict__ y) {
    const int T = 2048;
    __shared__ __attribute__((aligned(16))) ushort_t Plds[4 * 32 * 136];
    const int tid = threadIdx.x, lane = tid & 63, w = tid >> 6;
    const int quad = lane >> 4, l16 = lane & 15;
    const int unit = 4095 - ((int)blockIdx.x * 4 + w);  // heavy-first, block-balanced
    const int q32 = unit & 63, bh = unit >> 6;
    const int b = bh >> 4, h = bh & 15;
    const int q0 = q32 * 32;
    const int ktmax = q0 >> 7;
    ushort_t* Pw = Plds + w * (32 * 136);

    // Q fragments once, pre-scaled by 0.125*log2(e)
    bf16x8 qf[2][2];
    {
        const ushort_t* qb = qk + (size_t)(b * T + q0) * 2048 + h * 64 + quad * 8;
#pragma unroll
        for (int nt = 0; nt < 2; ++nt)
#pragma unroll
            for (int kd = 0; kd < 2; ++kd) {
                ushort8_t raw = *(const ushort8_t*)(qb + (size_t)(nt * 16 + l16) * 2048 + kd * 32);
                uint4_t dw;
#pragma unroll
                for (int j = 0; j < 4; ++j) {
                    float f0 = bf2f(raw[2 * j]) * ATT_SCALE;
                    float f1 = bf2f(raw[2 * j + 1]) * ATT_SCALE;
                    dw[j] = pack_trunc(f0, f1);
                }
                qf[nt][kd] = __builtin_bit_cast(bf16x8, dw);
            }
    }

    floatx4 o[2][4] = {};
    floatx4 lac[2] = {};
    float m_[2] = {-3e38f, -3e38f};

    const ushort_t* kb = qk + (size_t)(b * T) * 2048 + 1024 + h * 64 + quad * 8;
    const ushort_t* vb = vt + (size_t)bh * 64 * 2048 + quad * 8;

    for (int kt = 0; kt < ktmax; ++kt) {
        attn_step<false>(kb, vb, Pw, qf, o, lac, m_, quad, l16, 7, 0);
        kb += 128 * 2048;
        vb += 128;
    }
    attn_step<true>(kb, vb, Pw, qf, o, lac, m_, quad, l16,
                    2 * (q32 & 3) + 1, (q32 & 3) * 32);

    ushort_t* yb = y + (size_t)(b * T + q0) * 1024 + h * 64;
#pragma unroll
    for (int mtq = 0; mtq < 2; ++mtq)
#pragma unroll
        for (int r = 0; r < 4; ++r) {
            float inv = 1.0f / lac[mtq][r];  // ones-column: every l16 holds l
            int row = mtq * 16 + quad * 4 + r;
#pragma unroll
            for (int ntd = 0; ntd < 4; ++ntd)
                yb[(size_t)row * 1024 + ntd * 16 + l16] = f2bf(o[mtq][ntd][r] * inv);
        }
}

extern "C" void kernel_launch(void* const* d_in, const int* in_sizes, int n_in,
                              void* d_out, int out_size, void* d_ws, size_t ws_size,
                              hipStream_t stream) {
    const float* x = (const float*)d_in[0];
    const float* qkv_w = (const float*)d_in[1];
    const float* c_proj_w = (const float*)d_in[2];
    const float* c_proj_b = (const float*)d_in[3];
    float* out = (float*)d_out;

    const int M = 8192;  // B*T

    // ws: qk bf16 [8192 x 2048] = 32MB | vt bf16 [4][16][64][2048] = 16MB | y bf16 16MB
    ushort_t* qk = (ushort_t*)d_ws;
    ushort_t* vt = (ushort_t*)((char*)d_ws + (size_t)33554432);
    ushort_t* y = (ushort_t*)((char*)d_ws + (size_t)50331648);

    gemm_bt<float, 2><<<dim3(3072 / 128, M / 128), 256, 0, stream>>>(
        x, qkv_w, nullptr, qk, vt, M, 3072, 1024);

    rope_kernel<<<(M * 1024) / 256, 256, 0, stream>>>(qk);

    attn_kernel<<<dim3(1024), 256, 0, stream>>>(qk, vt, y);

    gemm_bt<ushort_t, 0><<<dim3(1024 / 128, M / 128), 256, 0, stream>>>(
        y, c_proj_w, c_proj_b, out, nullptr, M, 1024, 1024);
}

// Round 4
// 333.152 us; speedup vs baseline: 2.3051x; 1.6309x over previous
//
#include <hip/hip_runtime.h>

typedef unsigned short ushort_t;
typedef __bf16 bf16x8 __attribute__((ext_vector_type(8)));
typedef unsigned short ushort8_t __attribute__((ext_vector_type(8)));
typedef unsigned short ushort4_t __attribute__((ext_vector_type(4)));
typedef float floatx4 __attribute__((ext_vector_type(4)));
typedef unsigned int uint4_t __attribute__((ext_vector_type(4)));
typedef unsigned int uint2_t __attribute__((ext_vector_type(2)));

__device__ __forceinline__ ushort_t f2bf(float f) {
    unsigned int u = __float_as_uint(f);
    u += 0x7FFFu + ((u >> 16) & 1u);  // RNE
    return (ushort_t)(u >> 16);
}
__device__ __forceinline__ float bf2f(ushort_t b) {
    return __uint_as_float(((unsigned int)b) << 16);
}
__device__ __forceinline__ bf16x8 ld_frag(const ushort_t* p) {
    ushort8_t u = *(const ushort8_t*)p;
    return __builtin_bit_cast(bf16x8, u);
}
__device__ __forceinline__ unsigned pack_trunc(float lo, float hi) {
    return __builtin_amdgcn_perm(__float_as_uint(hi), __float_as_uint(lo), 0x07060302u);
}
__device__ __forceinline__ floatx4 mfma16(bf16x8 a, bf16x8 b, floatx4 c) {
    return __builtin_amdgcn_mfma_f32_16x16x32_bf16(a, b, c, 0, 0, 0);
}

// ---------------- GEMM (unchanged) ----------------
template <typename TA, int MODE>
__global__ __launch_bounds__(256) void gemm_bt(const TA* __restrict__ A,
                                               const float* __restrict__ B,
                                               const float* __restrict__ bias,
                                               void* __restrict__ Cout,
                                               ushort_t* __restrict__ vt,
                                               int M, int N, int K) {
    __shared__ __attribute__((aligned(16))) ushort_t As[128 * 32];
    __shared__ __attribute__((aligned(16))) ushort_t Bs[128 * 32];
    const int tid = threadIdx.x;
    const int lane = tid & 63, wave = tid >> 6;
    const int quad = lane >> 4, l16 = lane & 15;
    const int wm = wave & 1, wn = wave >> 1;
    const int m0 = blockIdx.y * 128, n0 = blockIdx.x * 128;

    floatx4 acc[4][4] = {};

    for (int k0 = 0; k0 < K; k0 += 32) {
        __syncthreads();
#pragma unroll
        for (int it = 0; it < 4; ++it) {
            int linear = it * 256 + tid;
            int row = linear >> 3;
            int c = (linear & 7) * 4;
            {
                const TA* src = A + (size_t)(m0 + row) * K + k0 + c;
                ushort4_t v;
                if constexpr (sizeof(TA) == 4) {
                    float4 f = *(const float4*)src;
                    v.x = f2bf(f.x); v.y = f2bf(f.y); v.z = f2bf(f.z); v.w = f2bf(f.w);
                } else {
                    v = *(const ushort4_t*)src;
                }
                *(ushort4_t*)&As[row * 32 + c] = v;
            }
            {
                const float* src = B + (size_t)(n0 + row) * K + k0 + c;
                float4 f = *(const float4*)src;
                ushort4_t v;
                v.x = f2bf(f.x); v.y = f2bf(f.y); v.z = f2bf(f.z); v.w = f2bf(f.w);
                *(ushort4_t*)&Bs[row * 32 + c] = v;
            }
        }
        __syncthreads();

        bf16x8 af[4], bfr[4];
#pragma unroll
        for (int mt = 0; mt < 4; ++mt)
            af[mt] = ld_frag(&As[(wm * 64 + mt * 16 + l16) * 32 + quad * 8]);
#pragma unroll
        for (int nt = 0; nt < 4; ++nt)
            bfr[nt] = ld_frag(&Bs[(wn * 64 + nt * 16 + l16) * 32 + quad * 8]);
#pragma unroll
        for (int mt = 0; mt < 4; ++mt)
#pragma unroll
            for (int nt = 0; nt < 4; ++nt)
                acc[mt][nt] = mfma16(af[mt], bfr[nt], acc[mt][nt]);
    }

#pragma unroll
    for (int mt = 0; mt < 4; ++mt) {
        int row = m0 + wm * 64 + mt * 16 + quad * 4;
#pragma unroll
        for (int nt = 0; nt < 4; ++nt) {
            int nglob = n0 + wn * 64 + nt * 16 + l16;
            if constexpr (MODE == 0) {
                float bv = bias ? bias[nglob] : 0.0f;
#pragma unroll
                for (int r = 0; r < 4; ++r)
                    ((float*)Cout)[(size_t)(row + r) * N + nglob] = acc[mt][nt][r] + bv;
            } else {
                if (nglob < 2048) {
#pragma unroll
                    for (int r = 0; r < 4; ++r)
                        ((ushort_t*)Cout)[(size_t)(row + r) * 2048 + nglob] =
                            f2bf(acc[mt][nt][r]);
                } else {
                    int d = nglob & 63, hh = (nglob >> 6) & 15;
                    int bb = row >> 11, t = row & 2047;
                    ushort4_t pk;
                    pk.x = f2bf(acc[mt][nt][0]);
                    pk.y = f2bf(acc[mt][nt][1]);
                    pk.z = f2bf(acc[mt][nt][2]);
                    pk.w = f2bf(acc[mt][nt][3]);
                    *(ushort4_t*)&vt[(((size_t)bb * 16 + hh) * 64 + d) * 2048 + t] = pk;
                }
            }
        }
    }
}

// ---------------- RoPE (unchanged) ----------------
__global__ __launch_bounds__(256) void rope_kernel(ushort_t* __restrict__ qk) {
    int idx = blockIdx.x * 256 + threadIdx.x;
    int i = idx & 31;
    int hh = (idx >> 5) & 31;
    int row = idx >> 10;
    int t = row & 2047;
    int col = hh * 64 + i;
    ushort_t* p1 = qk + (size_t)row * 2048 + col;
    ushort_t* p2 = p1 + 32;
    float x1 = bf2f(*p1), x2 = bf2f(*p2);
    float af = (i < 16) ? exp2f(-10.0f * (float)i / 15.0f) : 0.0f;
    float theta = (float)t * af;
    float s = sinf(theta), c = cosf(theta);
    *p1 = f2bf(x1 * c + x2 * s);
    *p2 = f2bf(-x1 * s + x2 * c);
}

// ---------------- Flash attention: balanced pairs + LDS-shared K/V ----------------
// Block = (b,h) x paired 128-row q-tiles (j, 15-j): exactly 17 kt-steps per block.
// 4 waves share LDS-staged K (swizzled) and V^T (stride-136); each wave owns 32
// q-rows. S^T = K*Q^T; softmax depth-2; l via ones-column MFMA; P per-wave LDS.
#define ATT_SCALE 0.18033688011112042f  /* 0.125 * log2(e) */

template <bool DIAG>
__device__ __forceinline__ void attn_step(
    const ushort_t* __restrict__ Ks, const ushort_t* __restrict__ Vt,
    ushort_t* __restrict__ Pw, const bf16x8 (&qf)[2][2],
    floatx4 (&o)[2][4], floatx4 (&lac)[2], float (&m_)[2],
    int quad, int l16, int sw8, int mhi, int qrel) {
    ushort8_t ou;
#pragma unroll
    for (int j = 0; j < 8; ++j) ou[j] = 0x3F80;  // bf16 1.0
    const bf16x8 vONE = __builtin_bit_cast(bf16x8, ou);

    floatx4 s[8][2];
#pragma unroll
    for (int mt = 0; mt < 8; ++mt) {
        if (DIAG && mt > mhi) continue;
        const ushort_t* kr = &Ks[(mt * 16 + l16) * 64];
        bf16x8 k0 = ld_frag(kr + ((quad * 8) ^ sw8));
        bf16x8 k1 = ld_frag(kr + ((32 + quad * 8) ^ sw8));
#pragma unroll
        for (int nt = 0; nt < 2; ++nt) {
            floatx4 z = {};
            z = mfma16(k0, qf[nt][0], z);
            s[mt][nt] = mfma16(k1, qf[nt][1], z);
        }
    }
    if (DIAG) {
#pragma unroll
        for (int mt = 0; mt < 8; ++mt) {
            if (mt > mhi) continue;
#pragma unroll
            for (int nt = 0; nt < 2; ++nt)
#pragma unroll
                for (int r = 0; r < 4; ++r)
                    if (mt * 16 + quad * 4 + r > qrel + nt * 16 + l16)
                        s[mt][nt][r] = -3e38f;
        }
    }
    float alpha_l[2];
#pragma unroll
    for (int nt = 0; nt < 2; ++nt) {
        float mx = -3e38f;
#pragma unroll
        for (int mt = 0; mt < 8; ++mt) {
            if (DIAG && mt > mhi) continue;
            mx = fmaxf(mx, fmaxf(fmaxf(s[mt][nt][0], s[mt][nt][1]),
                                 fmaxf(s[mt][nt][2], s[mt][nt][3])));
        }
        mx = fmaxf(mx, __shfl_xor(mx, 16));
        mx = fmaxf(mx, __shfl_xor(mx, 32));
        float mnew = fmaxf(m_[nt], mx);
        alpha_l[nt] = __builtin_amdgcn_exp2f(m_[nt] - mnew);
        m_[nt] = mnew;
#pragma unroll
        for (int mt = 0; mt < 8; ++mt) {
            if (DIAG && mt > mhi) continue;
#pragma unroll
            for (int r = 0; r < 4; ++r)
                s[mt][nt][r] = __builtin_amdgcn_exp2f(s[mt][nt][r] - mnew);
        }
    }
#pragma unroll
    for (int mtq = 0; mtq < 2; ++mtq)
#pragma unroll
        for (int r = 0; r < 4; ++r) {
            float ao = __shfl(alpha_l[mtq], quad * 4 + r);
            lac[mtq][r] *= ao;
#pragma unroll
            for (int ntd = 0; ntd < 4; ++ntd) o[mtq][ntd][r] *= ao;
        }
#pragma unroll
    for (int mt = 0; mt < 8; ++mt) {
        if (DIAG && mt > mhi) continue;
#pragma unroll
        for (int nt = 0; nt < 2; ++nt) {
            uint2_t pk;
            pk.x = pack_trunc(s[mt][nt][0], s[mt][nt][1]);
            pk.y = pack_trunc(s[mt][nt][2], s[mt][nt][3]);
            *(uint2_t*)&Pw[(nt * 16 + l16) * 136 + mt * 16 + quad * 4] = pk;
        }
    }
#pragma unroll
    for (int kc = 0; kc < 4; ++kc) {
        if (DIAG && kc > (mhi >> 1)) continue;
        bf16x8 ap0 = ld_frag(&Pw[l16 * 136 + kc * 32 + quad * 8]);
        bf16x8 ap1 = ld_frag(&Pw[(16 + l16) * 136 + kc * 32 + quad * 8]);
        lac[0] = mfma16(ap0, vONE, lac[0]);
        lac[1] = mfma16(ap1, vONE, lac[1]);
#pragma unroll
        for (int ntd = 0; ntd < 4; ++ntd) {
            bf16x8 bv = ld_frag(&Vt[(ntd * 16 + l16) * 136 + kc * 32 + quad * 8]);
            o[0][ntd] = mfma16(ap0, bv, o[0][ntd]);
            o[1][ntd] = mfma16(ap1, bv, o[1][ntd]);
        }
    }
}

__global__ __launch_bounds__(256, 2) void attn_kernel(const ushort_t* __restrict__ qk,
                                                      const ushort_t* __restrict__ vt,
                                                      ushort_t* __restrict__ y) {
    // LDS (ushort units): Ks 128x64 = 8192 | Vt 64x136 = 8704 | P 4x(32x136) = 17408
    __shared__ __attribute__((aligned(16))) ushort_t lds[34304];
    ushort_t* Ks = lds;
    ushort_t* Vt = lds + 8192;
    ushort_t* Pw0 = lds + 16896;

    const int tid = threadIdx.x, lane = tid & 63, w = tid >> 6;
    const int quad = lane >> 4, l16 = lane & 15;
    const int lrow = lane >> 3, lchunk = lane & 7;
    const int sw8 = 8 * (l16 >> 1);
    const int bh = (int)blockIdx.x >> 3, j = (int)blockIdx.x & 7;
    const int b = bh >> 4, h = bh & 15;
    ushort_t* Pw = Pw0 + w * 4352;

    const ushort_t* base_k = qk + (size_t)(b * 2048) * 2048 + 1024 + h * 64;
    const ushort_t* base_v = vt + (size_t)bh * 64 * 2048;

#pragma unroll 1
    for (int ph = 0; ph < 2; ++ph) {
        const int jj = ph ? (15 - j) : j;
        const int q0 = jj * 128 + w * 32;

        // Q fragments, pre-scaled by 0.125*log2(e)
        bf16x8 qf[2][2];
        {
            const ushort_t* qb = qk + (size_t)(b * 2048 + q0) * 2048 + h * 64 + quad * 8;
#pragma unroll
            for (int nt = 0; nt < 2; ++nt)
#pragma unroll
                for (int kd = 0; kd < 2; ++kd) {
                    ushort8_t raw =
                        *(const ushort8_t*)(qb + (size_t)(nt * 16 + l16) * 2048 + kd * 32);
                    uint4_t dw;
#pragma unroll
                    for (int jx = 0; jx < 4; ++jx) {
                        float f0 = bf2f(raw[2 * jx]) * ATT_SCALE;
                        float f1 = bf2f(raw[2 * jx + 1]) * ATT_SCALE;
                        dw[jx] = pack_trunc(f0, f1);
                    }
                    qf[nt][kd] = __builtin_bit_cast(bf16x8, dw);
                }
        }

        floatx4 o[2][4] = {};
        floatx4 lac[2] = {};
        float m_[2] = {-3e38f, -3e38f};

#pragma unroll 1
        for (int kt = 0; kt <= jj; ++kt) {
            __syncthreads();  // prior step's LDS reads done
            // stage K (swizzled chunks)
            {
                const ushort_t* gk = base_k + (size_t)(kt * 128) * 2048 + lchunk * 8;
#pragma unroll
                for (int i = 0; i < 4; ++i) {
                    int row = w * 32 + i * 8 + lrow;
                    ushort8_t v = *(const ushort8_t*)(gk + (size_t)row * 2048);
                    *(ushort8_t*)&Ks[row * 64 + 8 * (lchunk ^ ((row >> 1) & 7))] = v;
                }
            }
            // stage V^T (stride 136)
            {
                const ushort_t* gv = base_v + kt * 128;
#pragma unroll
                for (int i = 0; i < 4; ++i) {
                    int linear = i * 256 + tid;
                    int d = linear >> 4, c8 = linear & 15;
                    ushort8_t v = *(const ushort8_t*)(gv + (size_t)d * 2048 + c8 * 8);
                    *(ushort8_t*)&Vt[d * 136 + c8 * 8] = v;
                }
            }
            __syncthreads();  // K/V visible

            if (kt < jj)
                attn_step<false>(Ks, Vt, Pw, qf, o, lac, m_, quad, l16, sw8, 7, 0);
            else
                attn_step<true>(Ks, Vt, Pw, qf, o, lac, m_, quad, l16, sw8,
                                2 * w + 1, w * 32);
        }

        ushort_t* yb = y + (size_t)(b * 2048 + q0) * 1024 + h * 64;
#pragma unroll
        for (int mtq = 0; mtq < 2; ++mtq)
#pragma unroll
            for (int r = 0; r < 4; ++r) {
                float inv = 1.0f / lac[mtq][r];
                int row = mtq * 16 + quad * 4 + r;
#pragma unroll
                for (int ntd = 0; ntd < 4; ++ntd)
                    yb[(size_t)row * 1024 + ntd * 16 + l16] = f2bf(o[mtq][ntd][r] * inv);
            }
    }
}

extern "C" void kernel_launch(void* const* d_in, const int* in_sizes, int n_in,
                              void* d_out, int out_size, void* d_ws, size_t ws_size,
                              hipStream_t stream) {
    const float* x = (const float*)d_in[0];
    const float* qkv_w = (const float*)d_in[1];
    const float* c_proj_w = (const float*)d_in[2];
    const float* c_proj_b = (const float*)d_in[3];
    float* out = (float*)d_out;

    const int M = 8192;  // B*T

    // ws: qk bf16 [8192 x 2048] = 32MB | vt bf16 [4][16][64][2048] = 16MB | y bf16 16MB
    ushort_t* qk = (ushort_t*)d_ws;
    ushort_t* vt = (ushort_t*)((char*)d_ws + (size_t)33554432);
    ushort_t* y = (ushort_t*)((char*)d_ws + (size_t)50331648);

    gemm_bt<float, 2><<<dim3(3072 / 128, M / 128), 256, 0, stream>>>(
        x, qkv_w, nullptr, qk, vt, M, 3072, 1024);

    rope_kernel<<<(M * 1024) / 256, 256, 0, stream>>>(qk);

    attn_kernel<<<dim3(512), 256, 0, stream>>>(qk, vt, y);

    gemm_bt<ushort_t, 0><<<dim3(1024 / 128, M / 128), 256, 0, stream>>>(
        y, c_proj_w, c_proj_b, out, nullptr, M, 1024, 1024);
}

// Round 5
// 308.379 us; speedup vs baseline: 2.4903x; 1.0803x over previous
//
#include <hip/hip_runtime.h>

typedef unsigned short ushort_t;
typedef __bf16 bf16x8 __attribute__((ext_vector_type(8)));
typedef unsigned short ushort8_t __attribute__((ext_vector_type(8)));
typedef unsigned short ushort4_t __attribute__((ext_vector_type(4)));
typedef float floatx4 __attribute__((ext_vector_type(4)));
typedef unsigned int uint4_t __attribute__((ext_vector_type(4)));
typedef unsigned int uint2_t __attribute__((ext_vector_type(2)));

__device__ __forceinline__ ushort_t f2bf(float f) {
    unsigned int u = __float_as_uint(f);
    u += 0x7FFFu + ((u >> 16) & 1u);  // RNE
    return (ushort_t)(u >> 16);
}
__device__ __forceinline__ float bf2f(ushort_t b) {
    return __uint_as_float(((unsigned int)b) << 16);
}
__device__ __forceinline__ bf16x8 ld_frag(const ushort_t* p) {
    ushort8_t u = *(const ushort8_t*)p;
    return __builtin_bit_cast(bf16x8, u);
}
__device__ __forceinline__ unsigned pack_trunc(float lo, float hi) {
    return __builtin_amdgcn_perm(__float_as_uint(hi), __float_as_uint(lo), 0x07060302u);
}
__device__ __forceinline__ floatx4 mfma16(bf16x8 a, bf16x8 b, floatx4 c) {
    return __builtin_amdgcn_mfma_f32_16x16x32_bf16(a, b, c, 0, 0, 0);
}
// async global->LDS, 16B per lane; LDS dest = wave-uniform base + lane*16
__device__ __forceinline__ void async16(const ushort_t* g, ushort_t* l) {
    __builtin_amdgcn_global_load_lds((const __attribute__((address_space(1))) void*)g,
                                     (__attribute__((address_space(3))) void*)l, 16, 0, 0);
}

// ---------------- fp32 -> bf16 convert (8 elems/thread) ----------------
__global__ __launch_bounds__(256) void cvt_bf16(const float* __restrict__ src,
                                                ushort_t* __restrict__ dst, int n8) {
    int idx = blockIdx.x * 256 + threadIdx.x;
    if (idx >= n8) return;
    const float4* s = (const float4*)src + (size_t)idx * 2;
    float4 a = s[0], b = s[1];
    ushort8_t v;
    v[0] = f2bf(a.x); v[1] = f2bf(a.y); v[2] = f2bf(a.z); v[3] = f2bf(a.w);
    v[4] = f2bf(b.x); v[5] = f2bf(b.y); v[6] = f2bf(b.z); v[7] = f2bf(b.w);
    *(ushort8_t*)(dst + (size_t)idx * 8) = v;
}

// ---------------- GEMM: C[M,N] = A[M,K]*B[N,K]^T ----------------
// A: bf16, staged via global_load_lds (async). B: TB=float -> VALU convert-staging;
// TB=ushort_t -> async. MODE 0: fp32 out + bias. MODE 2: qkv split epilogue with
// FUSED RoPE (pair (d,d+32) == (nt,nt+2) at same lane; nt in {1,3} is identity)
// and V^T transposed store.
template <typename TB, int MODE>
__global__ __launch_bounds__(256) void gemm_a(const ushort_t* __restrict__ A,
                                              const TB* __restrict__ B,
                                              const float* __restrict__ bias,
                                              void* __restrict__ Cout,
                                              ushort_t* __restrict__ vt,
                                              int M, int N, int K) {
    constexpr bool BF16B = (sizeof(TB) == 2);
    __shared__ __attribute__((aligned(16))) ushort_t As[128 * 32];
    __shared__ __attribute__((aligned(16))) ushort_t Bs[128 * 32];
    const int tid = threadIdx.x;
    const int lane = tid & 63, wave = tid >> 6;
    const int quad = lane >> 4, l16 = lane & 15;
    const int wm = wave & 1, wn = wave >> 1;
    const int m0 = blockIdx.y * 128, n0 = blockIdx.x * 128;

    const ushort_t* ga = A + (size_t)(m0 + wave * 32 + (lane >> 2)) * K + (lane & 3) * 8;
    ushort_t* la = As + wave * 1024;
    const ushort_t* gb16 = nullptr;
    if constexpr (BF16B)
        gb16 = (const ushort_t*)B + (size_t)(n0 + wave * 32 + (lane >> 2)) * K + (lane & 3) * 8;
    ushort_t* lb = Bs + wave * 1024;

    floatx4 acc[4][4] = {};

    for (int k0 = 0; k0 < K; k0 += 32) {
        __syncthreads();
        async16(ga + k0, la);
        async16(ga + k0 + (size_t)16 * K, la + 512);
        if constexpr (BF16B) {
            async16(gb16 + k0, lb);
            async16(gb16 + k0 + (size_t)16 * K, lb + 512);
        } else {
#pragma unroll
            for (int it = 0; it < 4; ++it) {
                int linear = it * 256 + tid;
                int row = linear >> 3, c = (linear & 7) * 4;
                const float* src = (const float*)B + (size_t)(n0 + row) * K + k0 + c;
                float4 f = *(const float4*)src;
                ushort4_t v;
                v.x = f2bf(f.x); v.y = f2bf(f.y); v.z = f2bf(f.z); v.w = f2bf(f.w);
                *(ushort4_t*)&Bs[row * 32 + c] = v;
            }
        }
        __syncthreads();

        bf16x8 af[4], bfr[4];
#pragma unroll
        for (int mt = 0; mt < 4; ++mt)
            af[mt] = ld_frag(&As[(wm * 64 + mt * 16 + l16) * 32 + quad * 8]);
#pragma unroll
        for (int nt = 0; nt < 4; ++nt)
            bfr[nt] = ld_frag(&Bs[(wn * 64 + nt * 16 + l16) * 32 + quad * 8]);
#pragma unroll
        for (int mt = 0; mt < 4; ++mt)
#pragma unroll
            for (int nt = 0; nt < 4; ++nt)
                acc[mt][nt] = mfma16(af[mt], bfr[nt], acc[mt][nt]);
    }

    if constexpr (MODE == 2) {
        // fused RoPE on q/k heads (wave spans exactly one 64-wide head)
        if (n0 + wn * 64 < 2048) {
            float afreq = exp2f((float)l16 * (-10.0f / 15.0f));
#pragma unroll
            for (int mt = 0; mt < 4; ++mt) {
                int rowb = m0 + wm * 64 + mt * 16 + quad * 4;
#pragma unroll
                for (int r = 0; r < 4; ++r) {
                    int t = (rowb + r) & 2047;
                    float th = (float)t * afreq;
                    float sn = sinf(th), cs = cosf(th);
                    float q1 = acc[mt][0][r], q2 = acc[mt][2][r];
                    acc[mt][0][r] = q1 * cs + q2 * sn;
                    acc[mt][2][r] = -q1 * sn + q2 * cs;
                }
            }
        }
    }

#pragma unroll
    for (int mt = 0; mt < 4; ++mt) {
        int row = m0 + wm * 64 + mt * 16 + quad * 4;
#pragma unroll
        for (int nt = 0; nt < 4; ++nt) {
            int nglob = n0 + wn * 64 + nt * 16 + l16;
            if constexpr (MODE == 0) {
                float bv = bias ? bias[nglob] : 0.0f;
#pragma unroll
                for (int r = 0; r < 4; ++r)
                    ((float*)Cout)[(size_t)(row + r) * N + nglob] = acc[mt][nt][r] + bv;
            } else {
                if (nglob < 2048) {
#pragma unroll
                    for (int r = 0; r < 4; ++r)
                        ((ushort_t*)Cout)[(size_t)(row + r) * 2048 + nglob] =
                            f2bf(acc[mt][nt][r]);
                } else {
                    int d = nglob & 63, hh = (nglob >> 6) & 15;
                    int bb = row >> 11, t = row & 2047;
                    ushort4_t pk;
                    pk.x = f2bf(acc[mt][nt][0]);
                    pk.y = f2bf(acc[mt][nt][1]);
                    pk.z = f2bf(acc[mt][nt][2]);
                    pk.w = f2bf(acc[mt][nt][3]);
                    *(ushort4_t*)&vt[(((size_t)bb * 16 + hh) * 64 + d) * 2048 + t] = pk;
                }
            }
        }
    }
}

// ---------------- Flash attention (unchanged from round 3) ----------------
#define ATT_SCALE 0.18033688011112042f /* 0.125 * log2(e) */

template <bool DIAG>
__device__ __forceinline__ void attn_step(
    const ushort_t* __restrict__ Ks, const ushort_t* __restrict__ Vt,
    ushort_t* __restrict__ Pw, const bf16x8 (&qf)[2][2],
    floatx4 (&o)[2][4], floatx4 (&lac)[2], float (&m_)[2],
    int quad, int l16, int sw8, int mhi, int qrel) {
    ushort8_t ou;
#pragma unroll
    for (int j = 0; j < 8; ++j) ou[j] = 0x3F80;
    const bf16x8 vONE = __builtin_bit_cast(bf16x8, ou);

    floatx4 s[8][2];
#pragma unroll
    for (int mt = 0; mt < 8; ++mt) {
        if (DIAG && mt > mhi) continue;
        const ushort_t* kr = &Ks[(mt * 16 + l16) * 64];
        bf16x8 k0 = ld_frag(kr + ((quad * 8) ^ sw8));
        bf16x8 k1 = ld_frag(kr + ((32 + quad * 8) ^ sw8));
#pragma unroll
        for (int nt = 0; nt < 2; ++nt) {
            floatx4 z = {};
            z = mfma16(k0, qf[nt][0], z);
            s[mt][nt] = mfma16(k1, qf[nt][1], z);
        }
    }
    if (DIAG) {
#pragma unroll
        for (int mt = 0; mt < 8; ++mt) {
            if (mt > mhi) continue;
#pragma unroll
            for (int nt = 0; nt < 2; ++nt)
#pragma unroll
                for (int r = 0; r < 4; ++r)
                    if (mt * 16 + quad * 4 + r > qrel + nt * 16 + l16)
                        s[mt][nt][r] = -3e38f;
        }
    }
    float alpha_l[2];
#pragma unroll
    for (int nt = 0; nt < 2; ++nt) {
        float mx = -3e38f;
#pragma unroll
        for (int mt = 0; mt < 8; ++mt) {
            if (DIAG && mt > mhi) continue;
            mx = fmaxf(mx, fmaxf(fmaxf(s[mt][nt][0], s[mt][nt][1]),
                                 fmaxf(s[mt][nt][2], s[mt][nt][3])));
        }
        mx = fmaxf(mx, __shfl_xor(mx, 16));
        mx = fmaxf(mx, __shfl_xor(mx, 32));
        float mnew = fmaxf(m_[nt], mx);
        alpha_l[nt] = __builtin_amdgcn_exp2f(m_[nt] - mnew);
        m_[nt] = mnew;
#pragma unroll
        for (int mt = 0; mt < 8; ++mt) {
            if (DIAG && mt > mhi) continue;
#pragma unroll
            for (int r = 0; r < 4; ++r)
                s[mt][nt][r] = __builtin_amdgcn_exp2f(s[mt][nt][r] - mnew);
        }
    }
#pragma unroll
    for (int mtq = 0; mtq < 2; ++mtq)
#pragma unroll
        for (int r = 0; r < 4; ++r) {
            float ao = __shfl(alpha_l[mtq], quad * 4 + r);
            lac[mtq][r] *= ao;
#pragma unroll
            for (int ntd = 0; ntd < 4; ++ntd) o[mtq][ntd][r] *= ao;
        }
#pragma unroll
    for (int mt = 0; mt < 8; ++mt) {
        if (DIAG && mt > mhi) continue;
#pragma unroll
        for (int nt = 0; nt < 2; ++nt) {
            uint2_t pk;
            pk.x = pack_trunc(s[mt][nt][0], s[mt][nt][1]);
            pk.y = pack_trunc(s[mt][nt][2], s[mt][nt][3]);
            *(uint2_t*)&Pw[(nt * 16 + l16) * 136 + mt * 16 + quad * 4] = pk;
        }
    }
#pragma unroll
    for (int kc = 0; kc < 4; ++kc) {
        if (DIAG && kc > (mhi >> 1)) continue;
        bf16x8 ap0 = ld_frag(&Pw[l16 * 136 + kc * 32 + quad * 8]);
        bf16x8 ap1 = ld_frag(&Pw[(16 + l16) * 136 + kc * 32 + quad * 8]);
        lac[0] = mfma16(ap0, vONE, lac[0]);
        lac[1] = mfma16(ap1, vONE, lac[1]);
#pragma unroll
        for (int ntd = 0; ntd < 4; ++ntd) {
            bf16x8 bv = ld_frag(&Vt[(ntd * 16 + l16) * 136 + kc * 32 + quad * 8]);
            o[0][ntd] = mfma16(ap0, bv, o[0][ntd]);
            o[1][ntd] = mfma16(ap1, bv, o[1][ntd]);
        }
    }
}

__global__ __launch_bounds__(256, 2) void attn_kernel(const ushort_t* __restrict__ qk,
                                                      const ushort_t* __restrict__ vt,
                                                      ushort_t* __restrict__ y) {
    __shared__ __attribute__((aligned(16))) ushort_t lds[34304];
    ushort_t* Ks = lds;
    ushort_t* Vt = lds + 8192;
    ushort_t* Pw0 = lds + 16896;

    const int tid = threadIdx.x, lane = tid & 63, w = tid >> 6;
    const int quad = lane >> 4, l16 = lane & 15;
    const int lrow = lane >> 3, lchunk = lane & 7;
    const int sw8 = 8 * (l16 >> 1);
    const int bh = (int)blockIdx.x >> 3, j = (int)blockIdx.x & 7;
    const int b = bh >> 4, h = bh & 15;
    ushort_t* Pw = Pw0 + w * 4352;

    const ushort_t* base_k = qk + (size_t)(b * 2048) * 2048 + 1024 + h * 64;
    const ushort_t* base_v = vt + (size_t)bh * 64 * 2048;

#pragma unroll 1
    for (int ph = 0; ph < 2; ++ph) {
        const int jj = ph ? (15 - j) : j;
        const int q0 = jj * 128 + w * 32;

        bf16x8 qf[2][2];
        {
            const ushort_t* qb = qk + (size_t)(b * 2048 + q0) * 2048 + h * 64 + quad * 8;
#pragma unroll
            for (int nt = 0; nt < 2; ++nt)
#pragma unroll
                for (int kd = 0; kd < 2; ++kd) {
                    ushort8_t raw =
                        *(const ushort8_t*)(qb + (size_t)(nt * 16 + l16) * 2048 + kd * 32);
                    uint4_t dw;
#pragma unroll
                    for (int jx = 0; jx < 4; ++jx) {
                        float f0 = bf2f(raw[2 * jx]) * ATT_SCALE;
                        float f1 = bf2f(raw[2 * jx + 1]) * ATT_SCALE;
                        dw[jx] = pack_trunc(f0, f1);
                    }
                    qf[nt][kd] = __builtin_bit_cast(bf16x8, dw);
                }
        }

        floatx4 o[2][4] = {};
        floatx4 lac[2] = {};
        float m_[2] = {-3e38f, -3e38f};

#pragma unroll 1
        for (int kt = 0; kt <= jj; ++kt) {
            __syncthreads();
            {
                const ushort_t* gk = base_k + (size_t)(kt * 128) * 2048 + lchunk * 8;
#pragma unroll
                for (int i = 0; i < 4; ++i) {
                    int row = w * 32 + i * 8 + lrow;
                    ushort8_t v = *(const ushort8_t*)(gk + (size_t)row * 2048);
                    *(ushort8_t*)&Ks[row * 64 + 8 * (lchunk ^ ((row >> 1) & 7))] = v;
                }
            }
            {
                const ushort_t* gv = base_v + kt * 128;
#pragma unroll
                for (int i = 0; i < 4; ++i) {
                    int linear = i * 256 + tid;
                    int d = linear >> 4, c8 = linear & 15;
                    ushort8_t v = *(const ushort8_t*)(gv + (size_t)d * 2048 + c8 * 8);
                    *(ushort8_t*)&Vt[d * 136 + c8 * 8] = v;
                }
            }
            __syncthreads();

            if (kt < jj)
                attn_step<false>(Ks, Vt, Pw, qf, o, lac, m_, quad, l16, sw8, 7, 0);
            else
                attn_step<true>(Ks, Vt, Pw, qf, o, lac, m_, quad, l16, sw8,
                                2 * w + 1, w * 32);
        }

        ushort_t* yb = y + (size_t)(b * 2048 + q0) * 1024 + h * 64;
#pragma unroll
        for (int mtq = 0; mtq < 2; ++mtq)
#pragma unroll
            for (int r = 0; r < 4; ++r) {
                float inv = 1.0f / lac[mtq][r];
                int row = mtq * 16 + quad * 4 + r;
#pragma unroll
                for (int ntd = 0; ntd < 4; ++ntd)
                    yb[(size_t)row * 1024 + ntd * 16 + l16] = f2bf(o[mtq][ntd][r] * inv);
            }
    }
}

extern "C" void kernel_launch(void* const* d_in, const int* in_sizes, int n_in,
                              void* d_out, int out_size, void* d_ws, size_t ws_size,
                              hipStream_t stream) {
    const float* x = (const float*)d_in[0];
    const float* qkv_w = (const float*)d_in[1];
    const float* c_proj_w = (const float*)d_in[2];
    const float* c_proj_b = (const float*)d_in[3];
    float* out = (float*)d_out;

    const int M = 8192;  // B*T

    // ws (64 MB, time-multiplexed):
    //   [0,32M):  qk bf16 [8192 x 2048]            (gemm1 -> attn)
    //   [32,48M): vt bf16 [4][16][64][2048]        (gemm1 -> attn); first 2MB
    //             reused as wpb (c_proj_w bf16) after attn
    //   [48,64M): xb (x bf16) during gemm1; y bf16 after (attn -> gemm2)
    ushort_t* qk = (ushort_t*)d_ws;
    ushort_t* vt = (ushort_t*)((char*)d_ws + (size_t)33554432);
    ushort_t* wpb = vt;
    ushort_t* xb = (ushort_t*)((char*)d_ws + (size_t)50331648);
    ushort_t* y = xb;

    cvt_bf16<<<dim3(4096), 256, 0, stream>>>(x, xb, M * 1024 / 8);

    gemm_a<float, 2><<<dim3(3072 / 128, M / 128), 256, 0, stream>>>(
        xb, qkv_w, nullptr, qk, vt, M, 3072, 1024);

    attn_kernel<<<dim3(512), 256, 0, stream>>>(qk, vt, y);

    cvt_bf16<<<dim3(512), 256, 0, stream>>>(c_proj_w, wpb, 1024 * 1024 / 8);

    gemm_a<ushort_t, 0><<<dim3(1024 / 128, M / 128), 256, 0, stream>>>(
        y, wpb, c_proj_b, out, nullptr, M, 1024, 1024);
}

// Round 6
// 273.157 us; speedup vs baseline: 2.8114x; 1.1289x over previous
//
#include <hip/hip_runtime.h>

typedef unsigned short ushort_t;
typedef __bf16 bf16x8 __attribute__((ext_vector_type(8)));
typedef unsigned short ushort8_t __attribute__((ext_vector_type(8)));
typedef unsigned short ushort4_t __attribute__((ext_vector_type(4)));
typedef float floatx4 __attribute__((ext_vector_type(4)));
typedef unsigned int uint4_t __attribute__((ext_vector_type(4)));
typedef unsigned int uint2_t __attribute__((ext_vector_type(2)));

__device__ __forceinline__ ushort_t f2bf(float f) {
    unsigned int u = __float_as_uint(f);
    u += 0x7FFFu + ((u >> 16) & 1u);  // RNE
    return (ushort_t)(u >> 16);
}
__device__ __forceinline__ float bf2f(ushort_t b) {
    return __uint_as_float(((unsigned int)b) << 16);
}
__device__ __forceinline__ bf16x8 ld_frag(const ushort_t* p) {
    ushort8_t u = *(const ushort8_t*)p;
    return __builtin_bit_cast(bf16x8, u);
}
__device__ __forceinline__ unsigned pack_trunc(float lo, float hi) {
    return __builtin_amdgcn_perm(__float_as_uint(hi), __float_as_uint(lo), 0x07060302u);
}
__device__ __forceinline__ floatx4 mfma16(bf16x8 a, bf16x8 b, floatx4 c) {
    return __builtin_amdgcn_mfma_f32_16x16x32_bf16(a, b, c, 0, 0, 0);
}
// async global->LDS, 16B per lane; LDS dest = wave-uniform base + lane*16
__device__ __forceinline__ void async16(const ushort_t* g, ushort_t* l) {
    __builtin_amdgcn_global_load_lds((const __attribute__((address_space(1))) void*)g,
                                     (__attribute__((address_space(3))) void*)l, 16, 0, 0);
}

// ---------------- fp32 -> bf16 convert (8 elems/thread) ----------------
__global__ __launch_bounds__(256) void cvt_bf16(const float* __restrict__ src,
                                                ushort_t* __restrict__ dst, int n8) {
    int idx = blockIdx.x * 256 + threadIdx.x;
    if (idx >= n8) return;
    const float4* s = (const float4*)src + (size_t)idx * 2;
    float4 a = s[0], b = s[1];
    ushort8_t v;
    v[0] = f2bf(a.x); v[1] = f2bf(a.y); v[2] = f2bf(a.z); v[3] = f2bf(a.w);
    v[4] = f2bf(b.x); v[5] = f2bf(b.y); v[6] = f2bf(b.z); v[7] = f2bf(b.w);
    *(ushort8_t*)(dst + (size_t)idx * 8) = v;
}

// ---------------- GEMM: C[M,N] = A[M,K]*B[N,K]^T ----------------
// A,B bf16, both staged via global_load_lds (async, 16B). MODE 0: fp32 out + bias.
// MODE 2: qkv split epilogue with fused RoPE + V^T transposed store.
template <int MODE>
__global__ __launch_bounds__(256) void gemm_a(const ushort_t* __restrict__ A,
                                              const ushort_t* __restrict__ B,
                                              const float* __restrict__ bias,
                                              void* __restrict__ Cout,
                                              ushort_t* __restrict__ vt,
                                              int M, int N, int K) {
    __shared__ __attribute__((aligned(16))) ushort_t As[128 * 32];
    __shared__ __attribute__((aligned(16))) ushort_t Bs[128 * 32];
    const int tid = threadIdx.x;
    const int lane = tid & 63, wave = tid >> 6;
    const int quad = lane >> 4, l16 = lane & 15;
    const int wm = wave & 1, wn = wave >> 1;
    const int m0 = blockIdx.y * 128, n0 = blockIdx.x * 128;

    const ushort_t* ga = A + (size_t)(m0 + wave * 32 + (lane >> 2)) * K + (lane & 3) * 8;
    const ushort_t* gb = B + (size_t)(n0 + wave * 32 + (lane >> 2)) * K + (lane & 3) * 8;
    ushort_t* la = As + wave * 1024;
    ushort_t* lb = Bs + wave * 1024;

    floatx4 acc[4][4] = {};

    for (int k0 = 0; k0 < K; k0 += 32) {
        __syncthreads();
        async16(ga + k0, la);
        async16(ga + k0 + (size_t)16 * K, la + 512);
        async16(gb + k0, lb);
        async16(gb + k0 + (size_t)16 * K, lb + 512);
        __syncthreads();

        bf16x8 af[4], bfr[4];
#pragma unroll
        for (int mt = 0; mt < 4; ++mt)
            af[mt] = ld_frag(&As[(wm * 64 + mt * 16 + l16) * 32 + quad * 8]);
#pragma unroll
        for (int nt = 0; nt < 4; ++nt)
            bfr[nt] = ld_frag(&Bs[(wn * 64 + nt * 16 + l16) * 32 + quad * 8]);
#pragma unroll
        for (int mt = 0; mt < 4; ++mt)
#pragma unroll
            for (int nt = 0; nt < 4; ++nt)
                acc[mt][nt] = mfma16(af[mt], bfr[nt], acc[mt][nt]);
    }

    if constexpr (MODE == 2) {
        // fused RoPE on q/k heads (wave spans exactly one 64-wide head)
        if (n0 + wn * 64 < 2048) {
            float afreq = exp2f((float)l16 * (-10.0f / 15.0f));
#pragma unroll
            for (int mt = 0; mt < 4; ++mt) {
                int rowb = m0 + wm * 64 + mt * 16 + quad * 4;
#pragma unroll
                for (int r = 0; r < 4; ++r) {
                    int t = (rowb + r) & 2047;
                    float th = (float)t * afreq;
                    float sn, cs;
                    __sincosf(th, &sn, &cs);
                    float q1 = acc[mt][0][r], q2 = acc[mt][2][r];
                    acc[mt][0][r] = q1 * cs + q2 * sn;
                    acc[mt][2][r] = -q1 * sn + q2 * cs;
                }
            }
        }
    }

#pragma unroll
    for (int mt = 0; mt < 4; ++mt) {
        int row = m0 + wm * 64 + mt * 16 + quad * 4;
#pragma unroll
        for (int nt = 0; nt < 4; ++nt) {
            int nglob = n0 + wn * 64 + nt * 16 + l16;
            if constexpr (MODE == 0) {
                float bv = bias ? bias[nglob] : 0.0f;
#pragma unroll
                for (int r = 0; r < 4; ++r)
                    ((float*)Cout)[(size_t)(row + r) * N + nglob] = acc[mt][nt][r] + bv;
            } else {
                if (nglob < 2048) {
#pragma unroll
                    for (int r = 0; r < 4; ++r)
                        ((ushort_t*)Cout)[(size_t)(row + r) * 2048 + nglob] =
                            f2bf(acc[mt][nt][r]);
                } else {
                    int d = nglob & 63, hh = (nglob >> 6) & 15;
                    int bb = row >> 11, t = row & 2047;
                    ushort4_t pk;
                    pk.x = f2bf(acc[mt][nt][0]);
                    pk.y = f2bf(acc[mt][nt][1]);
                    pk.z = f2bf(acc[mt][nt][2]);
                    pk.w = f2bf(acc[mt][nt][3]);
                    *(ushort4_t*)&vt[(((size_t)bb * 16 + hh) * 64 + d) * 2048 + t] = pk;
                }
            }
        }
    }
}

// ---------------- Flash attention: balanced pairs, shared LDS K/V, reg prefetch ----
#define ATT_SCALE 0.18033688011112042f /* 0.125 * log2(e) */

template <bool DIAG>
__device__ __forceinline__ void attn_step(
    const ushort_t* __restrict__ Ks, const ushort_t* __restrict__ Vt,
    ushort_t* __restrict__ Pw, const bf16x8 (&qf)[2][2],
    floatx4 (&o)[2][4], floatx4 (&lac)[2], float (&m_)[2],
    int quad, int l16, int sw8, int mhi, int qrel) {
    ushort8_t ou;
#pragma unroll
    for (int j = 0; j < 8; ++j) ou[j] = 0x3F80;
    const bf16x8 vONE = __builtin_bit_cast(bf16x8, ou);

    floatx4 s[8][2];
#pragma unroll
    for (int mt = 0; mt < 8; ++mt) {
        if (DIAG && mt > mhi) continue;
        const ushort_t* kr = &Ks[(mt * 16 + l16) * 64];
        bf16x8 k0 = ld_frag(kr + ((quad * 8) ^ sw8));
        bf16x8 k1 = ld_frag(kr + ((32 + quad * 8) ^ sw8));
#pragma unroll
        for (int nt = 0; nt < 2; ++nt) {
            floatx4 z = {};
            z = mfma16(k0, qf[nt][0], z);
            s[mt][nt] = mfma16(k1, qf[nt][1], z);
        }
    }
    if (DIAG) {
#pragma unroll
        for (int mt = 0; mt < 8; ++mt) {
            if (mt > mhi) continue;
#pragma unroll
            for (int nt = 0; nt < 2; ++nt)
#pragma unroll
                for (int r = 0; r < 4; ++r)
                    if (mt * 16 + quad * 4 + r > qrel + nt * 16 + l16)
                        s[mt][nt][r] = -3e38f;
        }
    }
    float alpha_l[2];
#pragma unroll
    for (int nt = 0; nt < 2; ++nt) {
        float mx = -3e38f;
#pragma unroll
        for (int mt = 0; mt < 8; ++mt) {
            if (DIAG && mt > mhi) continue;
            mx = fmaxf(mx, fmaxf(fmaxf(s[mt][nt][0], s[mt][nt][1]),
                                 fmaxf(s[mt][nt][2], s[mt][nt][3])));
        }
        mx = fmaxf(mx, __shfl_xor(mx, 16));
        mx = fmaxf(mx, __shfl_xor(mx, 32));
        float mnew = fmaxf(m_[nt], mx);
        alpha_l[nt] = __builtin_amdgcn_exp2f(m_[nt] - mnew);
        m_[nt] = mnew;
#pragma unroll
        for (int mt = 0; mt < 8; ++mt) {
            if (DIAG && mt > mhi) continue;
#pragma unroll
            for (int r = 0; r < 4; ++r)
                s[mt][nt][r] = __builtin_amdgcn_exp2f(s[mt][nt][r] - mnew);
        }
    }
#pragma unroll
    for (int mtq = 0; mtq < 2; ++mtq)
#pragma unroll
        for (int r = 0; r < 4; ++r) {
            float ao = __shfl(alpha_l[mtq], quad * 4 + r);
            lac[mtq][r] *= ao;
#pragma unroll
            for (int ntd = 0; ntd < 4; ++ntd) o[mtq][ntd][r] *= ao;
        }
#pragma unroll
    for (int mt = 0; mt < 8; ++mt) {
        if (DIAG && mt > mhi) continue;
#pragma unroll
        for (int nt = 0; nt < 2; ++nt) {
            uint2_t pk;
            pk.x = pack_trunc(s[mt][nt][0], s[mt][nt][1]);
            pk.y = pack_trunc(s[mt][nt][2], s[mt][nt][3]);
            *(uint2_t*)&Pw[(nt * 16 + l16) * 136 + mt * 16 + quad * 4] = pk;
        }
    }
#pragma unroll
    for (int kc = 0; kc < 4; ++kc) {
        if (DIAG && kc > (mhi >> 1)) continue;
        bf16x8 ap0 = ld_frag(&Pw[l16 * 136 + kc * 32 + quad * 8]);
        bf16x8 ap1 = ld_frag(&Pw[(16 + l16) * 136 + kc * 32 + quad * 8]);
        lac[0] = mfma16(ap0, vONE, lac[0]);
        lac[1] = mfma16(ap1, vONE, lac[1]);
#pragma unroll
        for (int ntd = 0; ntd < 4; ++ntd) {
            bf16x8 bv = ld_frag(&Vt[(ntd * 16 + l16) * 136 + kc * 32 + quad * 8]);
            o[0][ntd] = mfma16(ap0, bv, o[0][ntd]);
            o[1][ntd] = mfma16(ap1, bv, o[1][ntd]);
        }
    }
}

__global__ __launch_bounds__(256, 2) void attn_kernel(const ushort_t* __restrict__ qk,
                                                      const ushort_t* __restrict__ vt,
                                                      ushort_t* __restrict__ y) {
    __shared__ __attribute__((aligned(16))) ushort_t lds[34304];
    ushort_t* Ks = lds;
    ushort_t* Vt = lds + 8192;
    ushort_t* Pw0 = lds + 16896;

    const int tid = threadIdx.x, lane = tid & 63, w = tid >> 6;
    const int quad = lane >> 4, l16 = lane & 15;
    const int lrow = lane >> 3, lchunk = lane & 7;
    const int sw8 = 8 * (l16 >> 1);
    const int bh = (int)blockIdx.x >> 3, j = (int)blockIdx.x & 7;
    const int b = bh >> 4, h = bh & 15;
    ushort_t* Pw = Pw0 + w * 4352;

    const ushort_t* base_k = qk + (size_t)(b * 2048) * 2048 + 1024 + h * 64;
    const ushort_t* base_v = vt + (size_t)bh * 64 * 2048;
    const int vd = w * 4 + (lane >> 4);  // this lane's V d-rows (stride 16)
    const int vc8 = lane & 15;

    ushort8_t kreg[4], vreg[4];
    auto load_kv = [&](int kt) {
        const ushort_t* gk = base_k + (size_t)(kt * 128) * 2048 + lchunk * 8;
#pragma unroll
        for (int i = 0; i < 4; ++i)
            kreg[i] = *(const ushort8_t*)(gk + (size_t)(w * 32 + i * 8 + lrow) * 2048);
        const ushort_t* gv = base_v + kt * 128;
#pragma unroll
        for (int i = 0; i < 4; ++i)
            vreg[i] = *(const ushort8_t*)(gv + (size_t)(i * 16 + vd) * 2048 + vc8 * 8);
    };
    auto store_kv = [&]() {
#pragma unroll
        for (int i = 0; i < 4; ++i) {
            int row = w * 32 + i * 8 + lrow;
            *(ushort8_t*)&Ks[row * 64 + 8 * (lchunk ^ ((row >> 1) & 7))] = kreg[i];
        }
#pragma unroll
        for (int i = 0; i < 4; ++i)
            *(ushort8_t*)&Vt[(i * 16 + vd) * 136 + vc8 * 8] = vreg[i];
    };

#pragma unroll 1
    for (int ph = 0; ph < 2; ++ph) {
        const int jj = ph ? (15 - j) : j;
        const int q0 = jj * 128 + w * 32;

        bf16x8 qf[2][2];
        {
            const ushort_t* qb = qk + (size_t)(b * 2048 + q0) * 2048 + h * 64 + quad * 8;
#pragma unroll
            for (int nt = 0; nt < 2; ++nt)
#pragma unroll
                for (int kd = 0; kd < 2; ++kd) {
                    ushort8_t raw =
                        *(const ushort8_t*)(qb + (size_t)(nt * 16 + l16) * 2048 + kd * 32);
                    uint4_t dw;
#pragma unroll
                    for (int jx = 0; jx < 4; ++jx) {
                        float f0 = bf2f(raw[2 * jx]) * ATT_SCALE;
                        float f1 = bf2f(raw[2 * jx + 1]) * ATT_SCALE;
                        dw[jx] = pack_trunc(f0, f1);
                    }
                    qf[nt][kd] = __builtin_bit_cast(bf16x8, dw);
                }
        }

        floatx4 o[2][4] = {};
        floatx4 lac[2] = {};
        float m_[2] = {-3e38f, -3e38f};

        load_kv(0);
#pragma unroll 1
        for (int kt = 0; kt <= jj; ++kt) {
            __syncthreads();  // prior step's LDS reads done
            store_kv();
            __syncthreads();  // K/V visible
            if (kt < jj) load_kv(kt + 1);  // prefetch overlaps compute

            if (kt < jj)
                attn_step<false>(Ks, Vt, Pw, qf, o, lac, m_, quad, l16, sw8, 7, 0);
            else
                attn_step<true>(Ks, Vt, Pw, qf, o, lac, m_, quad, l16, sw8,
                                2 * w + 1, w * 32);
        }

        ushort_t* yb = y + (size_t)(b * 2048 + q0) * 1024 + h * 64;
#pragma unroll
        for (int mtq = 0; mtq < 2; ++mtq)
#pragma unroll
            for (int r = 0; r < 4; ++r) {
                float inv = 1.0f / lac[mtq][r];
                int row = mtq * 16 + quad * 4 + r;
#pragma unroll
                for (int ntd = 0; ntd < 4; ++ntd)
                    yb[(size_t)row * 1024 + ntd * 16 + l16] = f2bf(o[mtq][ntd][r] * inv);
            }
    }
}

extern "C" void kernel_launch(void* const* d_in, const int* in_sizes, int n_in,
                              void* d_out, int out_size, void* d_ws, size_t ws_size,
                              hipStream_t stream) {
    const float* x = (const float*)d_in[0];
    const float* qkv_w = (const float*)d_in[1];
    const float* c_proj_w = (const float*)d_in[2];
    const float* c_proj_b = (const float*)d_in[3];
    float* out = (float*)d_out;

    const int M = 8192;  // B*T

    // Memory plan (time-multiplexed):
    //   d_out (32MB fp32): xb bf16 [8192x1024] during gemm1 (dead after);
    //                      final fp32 output written by gemm2 (full overwrite).
    //   ws[0,32M):  qk bf16 [8192 x 2048]       (gemm1 -> attn)
    //   ws[32,48M): vt bf16 [4][16][64][2048]   (gemm1 -> attn); first 2MB reused
    //               as wpb (c_proj_w bf16) after attn
    //   ws[48,64M): wb bf16 [3072x1024] (qkv_w) during gemm1 (dead after);
    //               y bf16 [8192x1024] written by attn (overwrites wb)
    ushort_t* qk = (ushort_t*)d_ws;
    ushort_t* vt = (ushort_t*)((char*)d_ws + (size_t)33554432);
    ushort_t* wpb = vt;
    ushort_t* wb = (ushort_t*)((char*)d_ws + (size_t)50331648);
    ushort_t* y = wb;
    ushort_t* xb = (ushort_t*)d_out;

    cvt_bf16<<<dim3(4096), 256, 0, stream>>>(x, xb, M * 1024 / 8);
    cvt_bf16<<<dim3(1536), 256, 0, stream>>>(qkv_w, wb, 3072 * 1024 / 8);

    gemm_a<2><<<dim3(3072 / 128, M / 128), 256, 0, stream>>>(
        xb, wb, nullptr, qk, vt, M, 3072, 1024);

    attn_kernel<<<dim3(512), 256, 0, stream>>>(qk, vt, y);

    cvt_bf16<<<dim3(512), 256, 0, stream>>>(c_proj_w, wpb, 1024 * 1024 / 8);

    gemm_a<0><<<dim3(1024 / 128, M / 128), 256, 0, stream>>>(
        y, wpb, c_proj_b, out, nullptr, M, 1024, 1024);
}

// Round 7
// 255.075 us; speedup vs baseline: 3.0107x; 1.0709x over previous
//
#include <hip/hip_runtime.h>

typedef unsigned short ushort_t;
typedef __bf16 bf16x8 __attribute__((ext_vector_type(8)));
typedef unsigned short ushort8_t __attribute__((ext_vector_type(8)));
typedef unsigned short ushort4_t __attribute__((ext_vector_type(4)));
typedef float floatx4 __attribute__((ext_vector_type(4)));
typedef unsigned int uint4_t __attribute__((ext_vector_type(4)));
typedef unsigned int uint2_t __attribute__((ext_vector_type(2)));

__device__ __forceinline__ ushort_t f2bf(float f) {
    unsigned int u = __float_as_uint(f);
    u += 0x7FFFu + ((u >> 16) & 1u);  // RNE
    return (ushort_t)(u >> 16);
}
__device__ __forceinline__ float bf2f(ushort_t b) {
    return __uint_as_float(((unsigned int)b) << 16);
}
__device__ __forceinline__ bf16x8 ld_frag(const ushort_t* p) {
    ushort8_t u = *(const ushort8_t*)p;
    return __builtin_bit_cast(bf16x8, u);
}
__device__ __forceinline__ unsigned pack_trunc(float lo, float hi) {
    return __builtin_amdgcn_perm(__float_as_uint(hi), __float_as_uint(lo), 0x07060302u);
}
__device__ __forceinline__ floatx4 mfma16(bf16x8 a, bf16x8 b, floatx4 c) {
    return __builtin_amdgcn_mfma_f32_16x16x32_bf16(a, b, c, 0, 0, 0);
}
// async global->LDS, 16B per lane; LDS dest = wave-uniform base + lane*16
__device__ __forceinline__ void async16(const ushort_t* g, ushort_t* l) {
    __builtin_amdgcn_global_load_lds((const __attribute__((address_space(1))) void*)g,
                                     (__attribute__((address_space(3))) void*)l, 16, 0, 0);
}

// ---------------- fp32 -> bf16 convert, two sources in one launch ----------------
__global__ __launch_bounds__(256) void cvt_dual(const float* __restrict__ s1,
                                                ushort_t* __restrict__ d1, int n1,
                                                const float* __restrict__ s2,
                                                ushort_t* __restrict__ d2, int n2) {
    int idx = blockIdx.x * 256 + threadIdx.x;
    const float* src;
    ushort_t* dst;
    if (idx < n1) {
        src = s1; dst = d1;
    } else {
        idx -= n1;
        if (idx >= n2) return;
        src = s2; dst = d2;
    }
    const float4* s = (const float4*)src + (size_t)idx * 2;
    float4 a = s[0], b = s[1];
    ushort8_t v;
    v[0] = f2bf(a.x); v[1] = f2bf(a.y); v[2] = f2bf(a.z); v[3] = f2bf(a.w);
    v[4] = f2bf(b.x); v[5] = f2bf(b.y); v[6] = f2bf(b.z); v[7] = f2bf(b.w);
    *(ushort8_t*)(dst + (size_t)idx * 8) = v;
}

// ---------------- GEMM: C[M,N] = A[M,K]*B[N,K]^T, K=1024 compile-time ----------------
// A,B bf16, both staged via global_load_lds; K-loop fully unrolled so global
// offsets fold into the instruction immediate (zero per-step VALU address math).
// MODE 0: fp32 out + bias. MODE 2: qkv split epilogue, fused RoPE, V^T store.
template <int MODE>
__global__ __launch_bounds__(256) void gemm_a(const ushort_t* __restrict__ A,
                                              const ushort_t* __restrict__ B,
                                              const float* __restrict__ bias,
                                              void* __restrict__ Cout,
                                              ushort_t* __restrict__ vt,
                                              int M, int N) {
    constexpr int K = 1024;
    __shared__ __attribute__((aligned(16))) ushort_t As[128 * 32];
    __shared__ __attribute__((aligned(16))) ushort_t Bs[128 * 32];
    const int tid = threadIdx.x;
    const int lane = tid & 63, wave = tid >> 6;
    const int quad = lane >> 4, l16 = lane & 15;
    const int wm = wave & 1, wn = wave >> 1;
    const int m0 = blockIdx.y * 128, n0 = blockIdx.x * 128;

    const ushort_t* ga = A + (size_t)(m0 + wave * 32 + (lane >> 2)) * K + (lane & 3) * 8;
    const ushort_t* gb = B + (size_t)(n0 + wave * 32 + (lane >> 2)) * K + (lane & 3) * 8;
    const ushort_t* ga2 = ga + 16 * K;
    const ushort_t* gb2 = gb + 16 * K;
    ushort_t* la = As + wave * 1024;
    ushort_t* lb = Bs + wave * 1024;

    floatx4 acc[4][4] = {};

#pragma unroll
    for (int k0 = 0; k0 < K; k0 += 32) {
        __syncthreads();
        async16(ga + k0, la);
        async16(ga2 + k0, la + 512);
        async16(gb + k0, lb);
        async16(gb2 + k0, lb + 512);
        __syncthreads();

        bf16x8 af[4], bfr[4];
#pragma unroll
        for (int mt = 0; mt < 4; ++mt)
            af[mt] = ld_frag(&As[(wm * 64 + mt * 16 + l16) * 32 + quad * 8]);
#pragma unroll
        for (int nt = 0; nt < 4; ++nt)
            bfr[nt] = ld_frag(&Bs[(wn * 64 + nt * 16 + l16) * 32 + quad * 8]);
#pragma unroll
        for (int mt = 0; mt < 4; ++mt)
#pragma unroll
            for (int nt = 0; nt < 4; ++nt)
                acc[mt][nt] = mfma16(af[mt], bfr[nt], acc[mt][nt]);
    }

    if constexpr (MODE == 2) {
        // fused RoPE on q/k heads (wave spans exactly one 64-wide head)
        if (n0 + wn * 64 < 2048) {
            float afreq = exp2f((float)l16 * (-10.0f / 15.0f));
#pragma unroll
            for (int mt = 0; mt < 4; ++mt) {
                int rowb = m0 + wm * 64 + mt * 16 + quad * 4;
#pragma unroll
                for (int r = 0; r < 4; ++r) {
                    int t = (rowb + r) & 2047;
                    float th = (float)t * afreq;
                    float sn, cs;
                    __sincosf(th, &sn, &cs);
                    float q1 = acc[mt][0][r], q2 = acc[mt][2][r];
                    acc[mt][0][r] = q1 * cs + q2 * sn;
                    acc[mt][2][r] = -q1 * sn + q2 * cs;
                }
            }
        }
    }

#pragma unroll
    for (int mt = 0; mt < 4; ++mt) {
        int row = m0 + wm * 64 + mt * 16 + quad * 4;
#pragma unroll
        for (int nt = 0; nt < 4; ++nt) {
            int nglob = n0 + wn * 64 + nt * 16 + l16;
            if constexpr (MODE == 0) {
                float bv = bias ? bias[nglob] : 0.0f;
#pragma unroll
                for (int r = 0; r < 4; ++r)
                    ((float*)Cout)[(size_t)(row + r) * N + nglob] = acc[mt][nt][r] + bv;
            } else {
                if (nglob < 2048) {
#pragma unroll
                    for (int r = 0; r < 4; ++r)
                        ((ushort_t*)Cout)[(size_t)(row + r) * 2048 + nglob] =
                            f2bf(acc[mt][nt][r]);
                } else {
                    int d = nglob & 63, hh = (nglob >> 6) & 15;
                    int bb = row >> 11, t = row & 2047;
                    ushort4_t pk;
                    pk.x = f2bf(acc[mt][nt][0]);
                    pk.y = f2bf(acc[mt][nt][1]);
                    pk.z = f2bf(acc[mt][nt][2]);
                    pk.w = f2bf(acc[mt][nt][3]);
                    *(ushort4_t*)&vt[(((size_t)bb * 16 + hh) * 64 + d) * 2048 + t] = pk;
                }
            }
        }
    }
}

// ---------------- Flash attention (unchanged from round 5) ----------------
#define ATT_SCALE 0.18033688011112042f /* 0.125 * log2(e) */

template <bool DIAG>
__device__ __forceinline__ void attn_step(
    const ushort_t* __restrict__ Ks, const ushort_t* __restrict__ Vt,
    ushort_t* __restrict__ Pw, const bf16x8 (&qf)[2][2],
    floatx4 (&o)[2][4], floatx4 (&lac)[2], float (&m_)[2],
    int quad, int l16, int sw8, int mhi, int qrel) {
    ushort8_t ou;
#pragma unroll
    for (int j = 0; j < 8; ++j) ou[j] = 0x3F80;
    const bf16x8 vONE = __builtin_bit_cast(bf16x8, ou);

    floatx4 s[8][2];
#pragma unroll
    for (int mt = 0; mt < 8; ++mt) {
        if (DIAG && mt > mhi) continue;
        const ushort_t* kr = &Ks[(mt * 16 + l16) * 64];
        bf16x8 k0 = ld_frag(kr + ((quad * 8) ^ sw8));
        bf16x8 k1 = ld_frag(kr + ((32 + quad * 8) ^ sw8));
#pragma unroll
        for (int nt = 0; nt < 2; ++nt) {
            floatx4 z = {};
            z = mfma16(k0, qf[nt][0], z);
            s[mt][nt] = mfma16(k1, qf[nt][1], z);
        }
    }
    if (DIAG) {
#pragma unroll
        for (int mt = 0; mt < 8; ++mt) {
            if (mt > mhi) continue;
#pragma unroll
            for (int nt = 0; nt < 2; ++nt)
#pragma unroll
                for (int r = 0; r < 4; ++r)
                    if (mt * 16 + quad * 4 + r > qrel + nt * 16 + l16)
                        s[mt][nt][r] = -3e38f;
        }
    }
    float alpha_l[2];
#pragma unroll
    for (int nt = 0; nt < 2; ++nt) {
        float mx = -3e38f;
#pragma unroll
        for (int mt = 0; mt < 8; ++mt) {
            if (DIAG && mt > mhi) continue;
            mx = fmaxf(mx, fmaxf(fmaxf(s[mt][nt][0], s[mt][nt][1]),
                                 fmaxf(s[mt][nt][2], s[mt][nt][3])));
        }
        mx = fmaxf(mx, __shfl_xor(mx, 16));
        mx = fmaxf(mx, __shfl_xor(mx, 32));
        float mnew = fmaxf(m_[nt], mx);
        alpha_l[nt] = __builtin_amdgcn_exp2f(m_[nt] - mnew);
        m_[nt] = mnew;
#pragma unroll
        for (int mt = 0; mt < 8; ++mt) {
            if (DIAG && mt > mhi) continue;
#pragma unroll
            for (int r = 0; r < 4; ++r)
                s[mt][nt][r] = __builtin_amdgcn_exp2f(s[mt][nt][r] - mnew);
        }
    }
#pragma unroll
    for (int mtq = 0; mtq < 2; ++mtq)
#pragma unroll
        for (int r = 0; r < 4; ++r) {
            float ao = __shfl(alpha_l[mtq], quad * 4 + r);
            lac[mtq][r] *= ao;
#pragma unroll
            for (int ntd = 0; ntd < 4; ++ntd) o[mtq][ntd][r] *= ao;
        }
#pragma unroll
    for (int mt = 0; mt < 8; ++mt) {
        if (DIAG && mt > mhi) continue;
#pragma unroll
        for (int nt = 0; nt < 2; ++nt) {
            uint2_t pk;
            pk.x = pack_trunc(s[mt][nt][0], s[mt][nt][1]);
            pk.y = pack_trunc(s[mt][nt][2], s[mt][nt][3]);
            *(uint2_t*)&Pw[(nt * 16 + l16) * 136 + mt * 16 + quad * 4] = pk;
        }
    }
#pragma unroll
    for (int kc = 0; kc < 4; ++kc) {
        if (DIAG && kc > (mhi >> 1)) continue;
        bf16x8 ap0 = ld_frag(&Pw[l16 * 136 + kc * 32 + quad * 8]);
        bf16x8 ap1 = ld_frag(&Pw[(16 + l16) * 136 + kc * 32 + quad * 8]);
        lac[0] = mfma16(ap0, vONE, lac[0]);
        lac[1] = mfma16(ap1, vONE, lac[1]);
#pragma unroll
        for (int ntd = 0; ntd < 4; ++ntd) {
            bf16x8 bv = ld_frag(&Vt[(ntd * 16 + l16) * 136 + kc * 32 + quad * 8]);
            o[0][ntd] = mfma16(ap0, bv, o[0][ntd]);
            o[1][ntd] = mfma16(ap1, bv, o[1][ntd]);
        }
    }
}

__global__ __launch_bounds__(256, 2) void attn_kernel(const ushort_t* __restrict__ qk,
                                                      const ushort_t* __restrict__ vt,
                                                      ushort_t* __restrict__ y) {
    __shared__ __attribute__((aligned(16))) ushort_t lds[34304];
    ushort_t* Ks = lds;
    ushort_t* Vt = lds + 8192;
    ushort_t* Pw0 = lds + 16896;

    const int tid = threadIdx.x, lane = tid & 63, w = tid >> 6;
    const int quad = lane >> 4, l16 = lane & 15;
    const int lrow = lane >> 3, lchunk = lane & 7;
    const int sw8 = 8 * (l16 >> 1);
    const int bh = (int)blockIdx.x >> 3, j = (int)blockIdx.x & 7;
    const int b = bh >> 4, h = bh & 15;
    ushort_t* Pw = Pw0 + w * 4352;

    const ushort_t* base_k = qk + (size_t)(b * 2048) * 2048 + 1024 + h * 64;
    const ushort_t* base_v = vt + (size_t)bh * 64 * 2048;
    const int vd = w * 4 + (lane >> 4);
    const int vc8 = lane & 15;

    ushort8_t kreg[4], vreg[4];
    auto load_kv = [&](int kt) {
        const ushort_t* gk = base_k + (size_t)(kt * 128) * 2048 + lchunk * 8;
#pragma unroll
        for (int i = 0; i < 4; ++i)
            kreg[i] = *(const ushort8_t*)(gk + (size_t)(w * 32 + i * 8 + lrow) * 2048);
        const ushort_t* gv = base_v + kt * 128;
#pragma unroll
        for (int i = 0; i < 4; ++i)
            vreg[i] = *(const ushort8_t*)(gv + (size_t)(i * 16 + vd) * 2048 + vc8 * 8);
    };
    auto store_kv = [&]() {
#pragma unroll
        for (int i = 0; i < 4; ++i) {
            int row = w * 32 + i * 8 + lrow;
            *(ushort8_t*)&Ks[row * 64 + 8 * (lchunk ^ ((row >> 1) & 7))] = kreg[i];
        }
#pragma unroll
        for (int i = 0; i < 4; ++i)
            *(ushort8_t*)&Vt[(i * 16 + vd) * 136 + vc8 * 8] = vreg[i];
    };

#pragma unroll 1
    for (int ph = 0; ph < 2; ++ph) {
        const int jj = ph ? (15 - j) : j;
        const int q0 = jj * 128 + w * 32;

        bf16x8 qf[2][2];
        {
            const ushort_t* qb = qk + (size_t)(b * 2048 + q0) * 2048 + h * 64 + quad * 8;
#pragma unroll
            for (int nt = 0; nt < 2; ++nt)
#pragma unroll
                for (int kd = 0; kd < 2; ++kd) {
                    ushort8_t raw =
                        *(const ushort8_t*)(qb + (size_t)(nt * 16 + l16) * 2048 + kd * 32);
                    uint4_t dw;
#pragma unroll
                    for (int jx = 0; jx < 4; ++jx) {
                        float f0 = bf2f(raw[2 * jx]) * ATT_SCALE;
                        float f1 = bf2f(raw[2 * jx + 1]) * ATT_SCALE;
                        dw[jx] = pack_trunc(f0, f1);
                    }
                    qf[nt][kd] = __builtin_bit_cast(bf16x8, dw);
                }
        }

        floatx4 o[2][4] = {};
        floatx4 lac[2] = {};
        float m_[2] = {-3e38f, -3e38f};

        load_kv(0);
#pragma unroll 1
        for (int kt = 0; kt <= jj; ++kt) {
            __syncthreads();
            store_kv();
            __syncthreads();
            if (kt < jj) load_kv(kt + 1);

            if (kt < jj)
                attn_step<false>(Ks, Vt, Pw, qf, o, lac, m_, quad, l16, sw8, 7, 0);
            else
                attn_step<true>(Ks, Vt, Pw, qf, o, lac, m_, quad, l16, sw8,
                                2 * w + 1, w * 32);
        }

        ushort_t* yb = y + (size_t)(b * 2048 + q0) * 1024 + h * 64;
#pragma unroll
        for (int mtq = 0; mtq < 2; ++mtq)
#pragma unroll
            for (int r = 0; r < 4; ++r) {
                float inv = 1.0f / lac[mtq][r];
                int row = mtq * 16 + quad * 4 + r;
#pragma unroll
                for (int ntd = 0; ntd < 4; ++ntd)
                    yb[(size_t)row * 1024 + ntd * 16 + l16] = f2bf(o[mtq][ntd][r] * inv);
            }
    }
}

extern "C" void kernel_launch(void* const* d_in, const int* in_sizes, int n_in,
                              void* d_out, int out_size, void* d_ws, size_t ws_size,
                              hipStream_t stream) {
    const float* x = (const float*)d_in[0];
    const float* qkv_w = (const float*)d_in[1];
    const float* c_proj_w = (const float*)d_in[2];
    const float* c_proj_b = (const float*)d_in[3];
    float* out = (float*)d_out;

    const int M = 8192;  // B*T

    // Memory plan (time-multiplexed):
    //   d_out (32MB fp32): xb bf16 [8192x1024] during gemm1 (dead after);
    //                      final fp32 output written by gemm2 (full overwrite).
    //   ws[0,32M):  qk bf16 [8192 x 2048]       (gemm1 -> attn)
    //   ws[32,48M): vt bf16 [4][16][64][2048]   (gemm1 -> attn); first 2MB reused
    //               as wpb (c_proj_w bf16) after attn
    //   ws[48,64M): wb bf16 [3072x1024] (qkv_w) during gemm1 (dead after);
    //               y bf16 [8192x1024] written by attn (overwrites wb)
    ushort_t* qk = (ushort_t*)d_ws;
    ushort_t* vt = (ushort_t*)((char*)d_ws + (size_t)33554432);
    ushort_t* wpb = vt;
    ushort_t* wb = (ushort_t*)((char*)d_ws + (size_t)50331648);
    ushort_t* y = wb;
    ushort_t* xb = (ushort_t*)d_out;

    cvt_dual<<<dim3(5632), 256, 0, stream>>>(x, xb, M * 1024 / 8,
                                             qkv_w, wb, 3072 * 1024 / 8);

    gemm_a<2><<<dim3(3072 / 128, M / 128), 256, 0, stream>>>(
        xb, wb, nullptr, qk, vt, M, 3072);

    attn_kernel<<<dim3(512), 256, 0, stream>>>(qk, vt, y);

    cvt_dual<<<dim3(512), 256, 0, stream>>>(c_proj_w, wpb, 1024 * 1024 / 8,
                                            nullptr, nullptr, 0);

    gemm_a<0><<<dim3(1024 / 128, M / 128), 256, 0, stream>>>(
        y, wpb, c_proj_b, out, nullptr, M, 1024);
}